// Round 5
// baseline (461.092 us; speedup 1.0000x reference)
//
#include <hip/hip_runtime.h>
#include <math.h>

#define N_NODES 100000
#define N_RELS  500
#define DIM     64
#define N_EDGES 1000000
#define SLOPE   0.01f
#define RSUB    16      // blocks per relation in pooling
#define SC_EDGES 2048   // edges per block in hist/scatter partition
#define NB_E    489     // ceil(N_EDGES / SC_EDGES)

// ---------------------------------------------------------------------------
// K0: fold the small matrices.
// ---------------------------------------------------------------------------
__global__ void k_fold(const float* __restrict__ W_ent, const float* __restrict__ b_ent,
                       const float* __restrict__ W_relL, const float* __restrict__ b_relL,
                       const float* __restrict__ W_rel2, const float* __restrict__ b_rel2,
                       const float* __restrict__ W_fc, const float* __restrict__ b_fc,
                       float* __restrict__ Wcat, float* __restrict__ dcat,
                       float* __restrict__ MW, float* __restrict__ MQ,
                       float* __restrict__ dW, float* __restrict__ dQ) {
    int idx = blockIdx.x * 256 + threadIdx.x;
    if (idx < 8192) {
        int k = idx >> 7;
        int j2 = idx & 127;
        int jj = j2 & 63;
        int off = (j2 >> 6) * 64;
        float s = 0.f;
        for (int i = 0; i < 64; i++) s += W_fc[jj*192 + off + i] * W_ent[i*64 + k];
        Wcat[k*128 + j2] = s;
    } else if (idx < 12288) {
        int rem = idx - 8192;
        int j = rem >> 6, i = rem & 63;
        float s = 0.f;
        for (int k = 0; k < 64; k++) s += W_fc[j*192 + 128 + k] * W_relL[k*64 + i];
        MW[j*64 + i] = s;
    } else if (idx < 16384) {
        int rem = idx - 12288;
        int j = rem >> 6, i = rem & 63;
        float s = 0.f;
        for (int k = 0; k < 64; k++) s += W_rel2[j*64 + k] * W_relL[k*64 + i];
        MQ[j*64 + i] = s;
    } else if (idx < 16512) {
        int j2 = idx - 16384;
        int jj = j2 & 63;
        int off = (j2 >> 6) * 64;
        float s = 0.f;
        for (int i = 0; i < 64; i++) s += b_ent[i] * W_fc[jj*192 + off + i];
        dcat[j2] = s;
    } else if (idx < 16640) {
        int rem = idx - 16512;
        int vec = rem >> 6, j = rem & 63;
        if (vec == 0) {
            float s = b_fc[j];
            for (int k = 0; k < 64; k++) s += b_relL[k] * W_fc[j*192 + 128 + k];
            dW[j] = s;
        } else {
            float s = b_rel2[j];
            for (int k = 0; k < 64; k++) s += b_relL[k] * W_rel2[j*64 + k];
            dQ[j] = s;
        }
    }
}

// ---------------------------------------------------------------------------
// K1: per-node projections as LDS-tiled register-blocked GEMM.
// ---------------------------------------------------------------------------
__global__ __launch_bounds__(256) void k_node(const float* __restrict__ ent,
        const float* __restrict__ Wcat, const float* __restrict__ dcat,
        const float* __restrict__ W_a,
        float* __restrict__ Uout, float* __restrict__ V,
        float* __restrict__ us, float* __restrict__ vs) {
    __shared__ float sA[64][68];
    __shared__ float sW[64][128];
    int t = threadIdx.x;
    int tile0 = blockIdx.x * 64;
    for (int i = t; i < 2048; i += 256)
        ((float4*)sW)[i] = ((const float4*)Wcat)[i];
    for (int f = t; f < 1024; f += 256) {
        int n = f >> 4, k4 = f & 15;
        float4 v4 = (tile0 + n < N_NODES)
            ? ((const float4*)(ent + (size_t)(tile0 + n) * 64))[k4]
            : make_float4(0.f, 0.f, 0.f, 0.f);
        *(float4*)&sA[n][k4 * 4] = v4;
    }
    __syncthreads();

    int ng = t >> 4;
    int jg = t & 15;
    int n0 = ng * 4;
    int j0 = jg * 8;

    float4 d0 = *(const float4*)(dcat + j0);
    float4 d1 = *(const float4*)(dcat + j0 + 4);
    float acc[4][8];
    #pragma unroll
    for (int a = 0; a < 4; a++) {
        acc[a][0] = d0.x; acc[a][1] = d0.y; acc[a][2] = d0.z; acc[a][3] = d0.w;
        acc[a][4] = d1.x; acc[a][5] = d1.y; acc[a][6] = d1.z; acc[a][7] = d1.w;
    }

    #pragma unroll 4
    for (int k = 0; k < 64; k++) {
        float4 w0 = *(const float4*)&sW[k][j0];
        float4 w1 = *(const float4*)&sW[k][j0 + 4];
        float e0 = sA[n0][k], e1 = sA[n0+1][k], e2 = sA[n0+2][k], e3 = sA[n0+3][k];
        float e[4] = {e0, e1, e2, e3};
        #pragma unroll
        for (int a = 0; a < 4; a++) {
            acc[a][0] += e[a] * w0.x; acc[a][1] += e[a] * w0.y;
            acc[a][2] += e[a] * w0.z; acc[a][3] += e[a] * w0.w;
            acc[a][4] += e[a] * w1.x; acc[a][5] += e[a] * w1.y;
            acc[a][6] += e[a] * w1.z; acc[a][7] += e[a] * w1.w;
        }
    }

    int jw = j0 & 63;
    float4 wa0 = *(const float4*)(W_a + jw);
    float4 wa1 = *(const float4*)(W_a + jw + 4);
    float part[4];
    #pragma unroll
    for (int a = 0; a < 4; a++) {
        part[a] = acc[a][0]*wa0.x + acc[a][1]*wa0.y + acc[a][2]*wa0.z + acc[a][3]*wa0.w
                + acc[a][4]*wa1.x + acc[a][5]*wa1.y + acc[a][6]*wa1.z + acc[a][7]*wa1.w;
    }
    #pragma unroll
    for (int m = 1; m <= 4; m <<= 1) {
        #pragma unroll
        for (int a = 0; a < 4; a++) part[a] += __shfl_xor(part[a], m, 64);
    }
    if ((jg & 7) == 0) {
        float* sv = (jg < 8) ? us : vs;
        #pragma unroll
        for (int a = 0; a < 4; a++)
            if (tile0 + n0 + a < N_NODES) sv[tile0 + n0 + a] = part[a];
    }

    #pragma unroll
    for (int a = 0; a < 4; a++) {
        int n = tile0 + n0 + a;
        if (n >= N_NODES) break;
        float4 o0 = make_float4(acc[a][0], acc[a][1], acc[a][2], acc[a][3]);
        float4 o1 = make_float4(acc[a][4], acc[a][5], acc[a][6], acc[a][7]);
        float* base = (jg < 8) ? (Uout + (size_t)n * 64 + j0) : (V + (size_t)n * 64 + (j0 - 64));
        *(float4*)(base) = o0;
        *(float4*)(base + 4) = o1;
    }
}

// K2: per-relation projections.
__global__ __launch_bounds__(256, 2) void k_relproj(const float* __restrict__ relE,
        const float* __restrict__ MW, const float* __restrict__ MQ,
        const float* __restrict__ dW, const float* __restrict__ dQ,
        const float* __restrict__ W_a,
        float* __restrict__ Wr, float* __restrict__ Qr, float* __restrict__ wsr) {
    int lane = threadIdx.x & 63;
    int wv = threadIdx.x >> 6;
    float mw[64], mq[64];
    #pragma unroll
    for (int i = 0; i < 64; i++) { mw[i] = MW[lane*64 + i]; mq[i] = MQ[lane*64 + i]; }
    float dw = dW[lane], dq = dQ[lane], wa = W_a[lane];
    int r = blockIdx.x * 4 + wv;
    if (r >= N_RELS) return;
    float e = relE[(size_t)r * 64 + lane];
    float w = dw, q = dq;
    #pragma unroll
    for (int i = 0; i < 64; i++) {
        float ei = __shfl(e, i, 64);
        w += ei * mw[i];
        q += ei * mq[i];
    }
    Wr[(size_t)r * 64 + lane] = w;
    Qr[(size_t)r * 64 + lane] = q;
    float tw = w * wa;
    #pragma unroll
    for (int o = 32; o; o >>= 1) tw += __shfl_xor(tw, o, 64);
    if (lane == 0) wsr[r] = tw;
}

__global__ void k_zero(int* __restrict__ a, int n) {
    int g = blockIdx.x * 256 + threadIdx.x;
    if (g < n) a[g] = 0;
}

// ---------------------------------------------------------------------------
// K3: histogram. 2048 edges/block, 8 edges/thread via int4 loads, batched
// independent atomics for ILP. rel via LDS + blkhist, src via global atomics.
// ---------------------------------------------------------------------------
__global__ __launch_bounds__(256) void k_hist(const int* __restrict__ src, const int* __restrict__ rel,
        int* __restrict__ cnt_src, int* __restrict__ cnt_rel, int* __restrict__ blkhist) {
    __shared__ int lcnt[N_RELS];
    int t = threadIdx.x;
    for (int r = t; r < N_RELS; r += 256) lcnt[r] = 0;
    __syncthreads();
    int base = blockIdx.x * SC_EDGES;
    if (base + SC_EDGES <= N_EDGES) {
        int e0 = base + t * 8;
        int4 sa = *(const int4*)(src + e0);
        int4 sb = *(const int4*)(src + e0 + 4);
        int4 ra = *(const int4*)(rel + e0);
        int4 rb = *(const int4*)(rel + e0 + 4);
        atomicAdd(&cnt_src[sa.x], 1); atomicAdd(&cnt_src[sa.y], 1);
        atomicAdd(&cnt_src[sa.z], 1); atomicAdd(&cnt_src[sa.w], 1);
        atomicAdd(&cnt_src[sb.x], 1); atomicAdd(&cnt_src[sb.y], 1);
        atomicAdd(&cnt_src[sb.z], 1); atomicAdd(&cnt_src[sb.w], 1);
        atomicAdd(&lcnt[ra.x], 1); atomicAdd(&lcnt[ra.y], 1);
        atomicAdd(&lcnt[ra.z], 1); atomicAdd(&lcnt[ra.w], 1);
        atomicAdd(&lcnt[rb.x], 1); atomicAdd(&lcnt[rb.y], 1);
        atomicAdd(&lcnt[rb.z], 1); atomicAdd(&lcnt[rb.w], 1);
    } else {
        for (int g = base + t; g < N_EDGES; g += 256) {
            atomicAdd(&cnt_src[src[g]], 1);
            atomicAdd(&lcnt[rel[g]], 1);
        }
    }
    __syncthreads();
    for (int r = t; r < N_RELS; r += 256) {
        int c = lcnt[r];
        blkhist[blockIdx.x * N_RELS + r] = c;
        if (c) atomicAdd(&cnt_rel[r], c);
    }
}

// exclusive scan of cnt over chunks of 1024; partials[b] = chunk total
__global__ void k_scan_local(const int* __restrict__ cnt, int* __restrict__ start,
                             int* __restrict__ partials, int n) {
    __shared__ int tot[256];
    int base = blockIdx.x * 1024;
    int t = threadIdx.x;
    int myv[4];
    int mySum = 0;
    for (int q = 0; q < 4; q++) {
        int g = base + t * 4 + q;
        int v = (g < n) ? cnt[g] : 0;
        myv[q] = v; mySum += v;
    }
    tot[t] = mySum;
    __syncthreads();
    for (int o = 1; o < 256; o <<= 1) {
        int v = (t >= o) ? tot[t - o] : 0;
        __syncthreads();
        tot[t] += v;
        __syncthreads();
    }
    int run = tot[t] - mySum;
    for (int q = 0; q < 4; q++) {
        int g = base + t * 4 + q;
        if (g < n) start[g] = run;
        run += myv[q];
    }
    if (t == 255) partials[blockIdx.x] = tot[255];
}

__global__ void k_scan_part(int* __restrict__ partials, int n) {
    __shared__ int s[256];
    int t = threadIdx.x;
    int v = (t < n) ? partials[t] : 0;
    s[t] = v;
    __syncthreads();
    for (int o = 1; o < 256; o <<= 1) {
        int u = (t >= o) ? s[t - o] : 0;
        __syncthreads();
        s[t] += u;
        __syncthreads();
    }
    if (t < n) partials[t] = s[t] - v;
}

__global__ void k_scan_add(int* __restrict__ start, const int* __restrict__ partials,
                           int* __restrict__ ctr, int n) {
    int g = blockIdx.x * 256 + threadIdx.x;
    if (g < n) {
        int v = start[g] + partials[g >> 10];
        start[g] = v;
        ctr[g] = v;
    }
}

__global__ void k_scan_small(const int* __restrict__ cnt, int* __restrict__ start, int n) {
    __shared__ int tot[256];
    int t = threadIdx.x;
    int myv[4];
    int mySum = 0;
    for (int q = 0; q < 4; q++) {
        int g = t * 4 + q;
        int v = (g < n) ? cnt[g] : 0;
        myv[q] = v; mySum += v;
    }
    tot[t] = mySum;
    __syncthreads();
    for (int o = 1; o < 256; o <<= 1) {
        int u = (t >= o) ? tot[t - o] : 0;
        __syncthreads();
        tot[t] += u;
        __syncthreads();
    }
    int run = tot[t] - mySum;
    for (int q = 0; q < 4; q++) {
        int g = t * 4 + q;
        if (g < n) start[g] = run;
        run += myv[q];
    }
}

__global__ void k_scan_relblk(const int* __restrict__ start_rel, const int* __restrict__ blkhist,
                              int* __restrict__ blkbase) {
    int r = blockIdx.x * 256 + threadIdx.x;
    if (r >= N_RELS) return;
    int run = start_rel[r];
    for (int b = 0; b < NB_E; b++) {
        int v = blkhist[b * N_RELS + r];
        blkbase[b * N_RELS + r] = run;
        run += v;
    }
}

// ---------------------------------------------------------------------------
// K5: scatter payloads. 2048 edges/block, 8 edges/thread, int4 loads, batched
// atomics for 8-deep ILP on the reserve->store chain.
// ---------------------------------------------------------------------------
__global__ __launch_bounds__(256) void k_scatter(const int* __restrict__ src, const int* __restrict__ dst,
        const int* __restrict__ rel, int* __restrict__ ctr_src,
        const int* __restrict__ blkbase, int2* __restrict__ pay_src, int2* __restrict__ pay_rel) {
    __shared__ int lbase[N_RELS];
    __shared__ int loff[N_RELS];
    int t = threadIdx.x;
    for (int r = t; r < N_RELS; r += 256) { lbase[r] = blkbase[blockIdx.x * N_RELS + r]; loff[r] = 0; }
    __syncthreads();
    int base = blockIdx.x * SC_EDGES;
    if (base + SC_EDGES <= N_EDGES) {
        int e0 = base + t * 8;
        int4 sa = *(const int4*)(src + e0);
        int4 sb = *(const int4*)(src + e0 + 4);
        int4 da = *(const int4*)(dst + e0);
        int4 db = *(const int4*)(dst + e0 + 4);
        int4 ra = *(const int4*)(rel + e0);
        int4 rb = *(const int4*)(rel + e0 + 4);
        int s[8] = {sa.x, sa.y, sa.z, sa.w, sb.x, sb.y, sb.z, sb.w};
        int d[8] = {da.x, da.y, da.z, da.w, db.x, db.y, db.z, db.w};
        int r8[8] = {ra.x, ra.y, ra.z, ra.w, rb.x, rb.y, rb.z, rb.w};
        int p[8], q[8];
        #pragma unroll
        for (int j = 0; j < 8; j++) p[j] = atomicAdd(&ctr_src[s[j]], 1);
        #pragma unroll
        for (int j = 0; j < 8; j++) q[j] = lbase[r8[j]] + atomicAdd(&loff[r8[j]], 1);
        #pragma unroll
        for (int j = 0; j < 8; j++) pay_src[p[j]] = make_int2(d[j], r8[j]);
        #pragma unroll
        for (int j = 0; j < 8; j++) pay_rel[q[j]] = make_int2(s[j], d[j]);
    } else {
        for (int g = base + t; g < N_EDGES; g += 256) {
            int s = src[g], d = dst[g], r = rel[g];
            int p = atomicAdd(&ctr_src[s], 1);
            pay_src[p] = make_int2(d, r);
            int q = lbase[r] + atomicAdd(&loff[r], 1);
            pay_rel[q] = make_int2(s, d);
        }
    }
}

// ---------------------------------------------------------------------------
// K6: fused scatter-softmax + neighbor aggregation. Wave per source node.
// ---------------------------------------------------------------------------
__global__ __launch_bounds__(256) void k_attn(const int2* __restrict__ pay,
        const int* __restrict__ start_src, const int* __restrict__ cnt_src,
        const float* __restrict__ us, const float* __restrict__ vs,
        const float* __restrict__ wsr, const float* __restrict__ V,
        const float* __restrict__ Wr, const float* __restrict__ b_a_p,
        float* __restrict__ h) {
    int lane = threadIdx.x & 63;
    int wv = threadIdx.x >> 6;
    int n = blockIdx.x * 4 + wv;
    if (n >= N_NODES) return;
    int st = start_src[n];
    int cnt = cnt_src[n];
    if (cnt == 0) { h[(size_t)n * 64 + lane] = 0.f; return; }
    float ba = b_a_p[0];
    float usn = us[n];

    if (cnt <= 64) {
        int2 pe = (lane < cnt) ? pay[st + lane] : make_int2(0, 0);
        float bexp = 0.f;
        if (lane < cnt) {
            float s = usn + vs[pe.x] + wsr[pe.y] + ba;
            s = s > 0.f ? s : SLOPE * s;
            bexp = expf(s);
        }
        float bp = bexp;
        #pragma unroll
        for (int o = 32; o; o >>= 1) bp += __shfl_xor(bp, o, 64);
        float inv = 1.f / bp;
        int sub = lane >> 4;
        int li = lane & 15;
        float4 acc = make_float4(0.f, 0.f, 0.f, 0.f);
        int groups = (cnt + 3) >> 2;
        for (int g = 0; g < groups; g++) {
            int esel = 4 * g + sub;
            float be = __shfl(bexp, esel, 64);
            int de = __shfl(pe.x, esel, 64);
            int re = __shfl(pe.y, esel, 64);
            float4 vv = *(const float4*)(V + (size_t)de * 64 + li * 4);
            float4 wvv = *(const float4*)(Wr + (size_t)re * 64 + li * 4);
            acc.x += be * (vv.x + wvv.x);
            acc.y += be * (vv.y + wvv.y);
            acc.z += be * (vv.z + wvv.z);
            acc.w += be * (vv.w + wvv.w);
        }
        acc.x += __shfl_xor(acc.x, 16, 64); acc.x += __shfl_xor(acc.x, 32, 64);
        acc.y += __shfl_xor(acc.y, 16, 64); acc.y += __shfl_xor(acc.y, 32, 64);
        acc.z += __shfl_xor(acc.z, 16, 64); acc.z += __shfl_xor(acc.z, 32, 64);
        acc.w += __shfl_xor(acc.w, 16, 64); acc.w += __shfl_xor(acc.w, 32, 64);
        if (lane < 16) {
            float4 u = *(const float4*)(h + (size_t)n * 64 + lane * 4);
            float4 o4;
            o4.x = u.x + acc.x * inv;
            o4.y = u.y + acc.y * inv;
            o4.z = u.z + acc.z * inv;
            o4.w = u.w + acc.w * inv;
            *(float4*)(h + (size_t)n * 64 + lane * 4) = o4;
        }
        return;
    }

    float bp = 0.f;
    for (int k = lane; k < cnt; k += 64) {
        int2 p = pay[st + k];
        float s = usn + vs[p.x] + wsr[p.y] + ba;
        s = s > 0.f ? s : SLOPE * s;
        bp += expf(s);
    }
    #pragma unroll
    for (int o = 32; o; o >>= 1) bp += __shfl_xor(bp, o, 64);
    float inv = 1.f / bp;
    float acc = 0.f;
    for (int k = 0; k < cnt; k++) {
        int2 p = pay[st + k];
        float s = usn + vs[p.x] + wsr[p.y] + ba;
        s = s > 0.f ? s : SLOPE * s;
        float b = expf(s);
        acc += b * (V[(size_t)p.x * 64 + lane] + Wr[(size_t)p.y * 64 + lane]);
    }
    float u = h[(size_t)n * 64 + lane];
    h[(size_t)n * 64 + lane] = u + acc * inv;
}

// ---------------------------------------------------------------------------
// K7: relation pooling (float4 gathers, pipelined pay prefetch, LDS reduce).
// ---------------------------------------------------------------------------
__global__ __launch_bounds__(256) void k_relpool(const int2* __restrict__ pay,
        const int* __restrict__ start_rel, const int* __restrict__ cnt_rel,
        const float* __restrict__ h, float* __restrict__ acc_rel) {
    int r = blockIdx.x / RSUB;
    int sub = blockIdx.x % RSUB;
    int st = start_rel[r];
    int cnt = cnt_rel[r];
    int t = threadIdx.x;
    int j = t >> 5;
    int side = (t >> 4) & 1;
    int li = t & 15;

    int chunk = (cnt + RSUB - 1) / RSUB;
    int k0 = sub * chunk;
    int k1 = min(k0 + chunk, cnt);
    int len = k1 - k0;

    float4 acc = make_float4(0.f, 0.f, 0.f, 0.f);
    if (len > 0) {
        int steps = (len + 7) >> 3;
        int k = k0 + j;
        bool v = (j < len);
        int2 p = v ? pay[st + k] : make_int2(0, 0);
        for (int it = 0; it < steps; it++) {
            k += 8;
            bool vn = (it + 1 < steps) && (k < k1);
            int2 pn = vn ? pay[st + k] : make_int2(0, 0);
            int idx = side ? p.y : p.x;
            float4 hv = *(const float4*)(h + (size_t)idx * 64 + li * 4);
            if (v) {
                acc.x += hv.x; acc.y += hv.y; acc.z += hv.z; acc.w += hv.w;
            }
            p = pn; v = vn;
        }
    }
    __shared__ float4 red[256];
    red[t] = acc;
    __syncthreads();
    if (t < 128) {
        float4 a = red[t], b = red[t + 128];
        a.x += b.x; a.y += b.y; a.z += b.z; a.w += b.w;
        red[t] = a;
    }
    __syncthreads();
    if (t < 64) {
        float4 a = red[t], b = red[t + 64];
        a.x += b.x; a.y += b.y; a.z += b.z; a.w += b.w;
        red[t] = a;
    }
    __syncthreads();
    if (t < 32) {
        float4 a = red[t], b = red[t + 32];
        a.x += b.x; a.y += b.y; a.z += b.z; a.w += b.w;
        float* dstp = &acc_rel[r * 128 + side * 64 + li * 4];
        atomicAdd(dstp + 0, a.x);
        atomicAdd(dstp + 1, a.y);
        atomicAdd(dstp + 2, a.z);
        atomicAdd(dstp + 3, a.w);
    }
}

// K8: mean + h_rel = mean @ W_rel3.T + b_rel3
__global__ void k_relfin(const float* __restrict__ acc_rel, const int* __restrict__ cnt_rel,
                         const float* __restrict__ Qr, const float* __restrict__ W_rel3,
                         const float* __restrict__ b_rel3, float* __restrict__ out) {
    int g = blockIdx.x * 256 + threadIdx.x;
    if (g >= N_RELS * 64) return;
    int r = g >> 6;
    int j = g & 63;
    int cnt = cnt_rel[r];
    float invc = 1.f / (float)(cnt > 0 ? cnt : 1);
    float s = b_rel3[j];
    for (int k = 0; k < 128; k++) s += acc_rel[r * 128 + k] * invc * W_rel3[j * 192 + k];
    if (cnt > 0)
        for (int k = 0; k < 64; k++) s += Qr[r * 64 + k] * W_rel3[j * 192 + 128 + k];
    out[g] = s;
}

extern "C" void kernel_launch(void* const* d_in, const int* in_sizes, int n_in,
                              void* d_out, int out_size, void* d_ws, size_t ws_size,
                              hipStream_t stream) {
    const float* ent    = (const float*)d_in[0];
    const float* relE   = (const float*)d_in[1];
    const float* W_ent  = (const float*)d_in[2];
    const float* b_ent  = (const float*)d_in[3];
    const float* W_relL = (const float*)d_in[4];
    const float* b_relL = (const float*)d_in[5];
    const float* W_rel2 = (const float*)d_in[6];
    const float* b_rel2 = (const float*)d_in[7];
    const float* W_rel3 = (const float*)d_in[8];
    const float* b_rel3 = (const float*)d_in[9];
    const float* W_a    = (const float*)d_in[10];
    const float* b_a    = (const float*)d_in[11];
    const float* W_fc   = (const float*)d_in[12];
    const float* b_fc   = (const float*)d_in[13];
    const int* src = (const int*)d_in[14];
    const int* dst = (const int*)d_in[15];
    const int* rel = (const int*)d_in[16];
    float* out = (float*)d_out;

    char* ws = (char*)d_ws;
    size_t off = 0;
    auto alloc = [&](size_t bytes) -> void* {
        void* p = ws + off;
        off += (bytes + 255) & ~(size_t)255;
        return p;
    };
    float* Wcat = (float*)alloc(8192 * 4);
    float* dcat = (float*)alloc(128 * 4);
    float* MW  = (float*)alloc(4096 * 4);
    float* MQ  = (float*)alloc(4096 * 4);
    float* dW  = (float*)alloc(64 * 4);
    float* dQ  = (float*)alloc(64 * 4);
    float* V   = (float*)alloc((size_t)N_NODES * 64 * 4);
    float* us  = (float*)alloc((size_t)N_NODES * 4);
    float* vs  = (float*)alloc((size_t)N_NODES * 4);
    float* Wr  = (float*)alloc((size_t)N_RELS * 64 * 4);
    float* Qr  = (float*)alloc((size_t)N_RELS * 64 * 4);
    float* wsr = (float*)alloc((size_t)N_RELS * 4);
    int* cnt_src   = (int*)alloc((size_t)N_NODES * 4);
    int* start_src = (int*)alloc((size_t)N_NODES * 4);
    int* ctr_src   = (int*)alloc((size_t)N_NODES * 4);
    int* partials  = (int*)alloc(256 * 4);
    int* cnt_rel   = (int*)alloc((size_t)N_RELS * 4);
    int* start_rel = (int*)alloc((size_t)N_RELS * 4);
    int* blkhist   = (int*)alloc((size_t)NB_E * N_RELS * 4);
    int* blkbase   = (int*)alloc((size_t)NB_E * N_RELS * 4);
    int2* pay_src  = (int2*)alloc((size_t)N_EDGES * 8);
    int2* pay_rel  = (int2*)alloc((size_t)N_EDGES * 8);
    float* acc_rel = (float*)alloc((size_t)N_RELS * 128 * 4);

    k_zero<<<(N_NODES + 255) / 256, 256, 0, stream>>>(cnt_src, N_NODES);
    k_zero<<<(N_RELS + 255) / 256, 256, 0, stream>>>(cnt_rel, N_RELS);
    k_zero<<<(N_RELS * 128 + 255) / 256, 256, 0, stream>>>((int*)acc_rel, N_RELS * 128);

    k_fold<<<65, 256, 0, stream>>>(W_ent, b_ent, W_relL, b_relL, W_rel2, b_rel2,
                                   W_fc, b_fc, Wcat, dcat, MW, MQ, dW, dQ);
    k_node<<<(N_NODES + 63) / 64, 256, 0, stream>>>(ent, Wcat, dcat, W_a, out, V, us, vs);
    k_relproj<<<125, 256, 0, stream>>>(relE, MW, MQ, dW, dQ, W_a, Wr, Qr, wsr);
    k_hist<<<NB_E, 256, 0, stream>>>(src, rel, cnt_src, cnt_rel, blkhist);
    k_scan_local<<<98, 256, 0, stream>>>(cnt_src, start_src, partials, N_NODES);
    k_scan_part<<<1, 256, 0, stream>>>(partials, 98);
    k_scan_add<<<(N_NODES + 255) / 256, 256, 0, stream>>>(start_src, partials, ctr_src, N_NODES);
    k_scan_small<<<1, 256, 0, stream>>>(cnt_rel, start_rel, N_RELS);
    k_scan_relblk<<<2, 256, 0, stream>>>(start_rel, blkhist, blkbase);
    k_scatter<<<NB_E, 256, 0, stream>>>(src, dst, rel, ctr_src, blkbase, pay_src, pay_rel);
    k_attn<<<N_NODES / 4, 256, 0, stream>>>(pay_src, start_src, cnt_src,
                                            us, vs, wsr, V, Wr, b_a, out);
    k_relpool<<<N_RELS * RSUB, 256, 0, stream>>>(pay_rel, start_rel, cnt_rel, out, acc_rel);
    k_relfin<<<(N_RELS * 64 + 255) / 256, 256, 0, stream>>>(acc_rel, cnt_rel, Qr, W_rel3,
                                                            b_rel3, out + (size_t)N_NODES * 64);
}

// Round 6
// 408.970 us; speedup vs baseline: 1.1274x; 1.1274x over previous
//
#include <hip/hip_runtime.h>
#include <math.h>

#define N_NODES 100000
#define N_RELS  500
#define DIM     64
#define N_EDGES 1000000
#define SLOPE   0.01f
#define RSUB    16      // blocks per relation in pooling
#define SC_EDGES 2048   // edges per block in hist/scatter partition
#define NB_E    489     // ceil(N_EDGES / SC_EDGES)

// ---------------------------------------------------------------------------
// K0: fold the small matrices.
// ---------------------------------------------------------------------------
__global__ void k_fold(const float* __restrict__ W_ent, const float* __restrict__ b_ent,
                       const float* __restrict__ W_relL, const float* __restrict__ b_relL,
                       const float* __restrict__ W_rel2, const float* __restrict__ b_rel2,
                       const float* __restrict__ W_fc, const float* __restrict__ b_fc,
                       float* __restrict__ Wcat, float* __restrict__ dcat,
                       float* __restrict__ MW, float* __restrict__ MQ,
                       float* __restrict__ dW, float* __restrict__ dQ) {
    int idx = blockIdx.x * 256 + threadIdx.x;
    if (idx < 8192) {
        int k = idx >> 7;
        int j2 = idx & 127;
        int jj = j2 & 63;
        int off = (j2 >> 6) * 64;
        float s = 0.f;
        for (int i = 0; i < 64; i++) s += W_fc[jj*192 + off + i] * W_ent[i*64 + k];
        Wcat[k*128 + j2] = s;
    } else if (idx < 12288) {
        int rem = idx - 8192;
        int j = rem >> 6, i = rem & 63;
        float s = 0.f;
        for (int k = 0; k < 64; k++) s += W_fc[j*192 + 128 + k] * W_relL[k*64 + i];
        MW[j*64 + i] = s;
    } else if (idx < 16384) {
        int rem = idx - 12288;
        int j = rem >> 6, i = rem & 63;
        float s = 0.f;
        for (int k = 0; k < 64; k++) s += W_rel2[j*64 + k] * W_relL[k*64 + i];
        MQ[j*64 + i] = s;
    } else if (idx < 16512) {
        int j2 = idx - 16384;
        int jj = j2 & 63;
        int off = (j2 >> 6) * 64;
        float s = 0.f;
        for (int i = 0; i < 64; i++) s += b_ent[i] * W_fc[jj*192 + off + i];
        dcat[j2] = s;
    } else if (idx < 16640) {
        int rem = idx - 16512;
        int vec = rem >> 6, j = rem & 63;
        if (vec == 0) {
            float s = b_fc[j];
            for (int k = 0; k < 64; k++) s += b_relL[k] * W_fc[j*192 + 128 + k];
            dW[j] = s;
        } else {
            float s = b_rel2[j];
            for (int k = 0; k < 64; k++) s += b_relL[k] * W_rel2[j*64 + k];
            dQ[j] = s;
        }
    }
}

// ---------------------------------------------------------------------------
// K1: per-node projections as LDS-tiled register-blocked GEMM.
// ---------------------------------------------------------------------------
__global__ __launch_bounds__(256) void k_node(const float* __restrict__ ent,
        const float* __restrict__ Wcat, const float* __restrict__ dcat,
        const float* __restrict__ W_a,
        float* __restrict__ Uout, float* __restrict__ V,
        float* __restrict__ us, float* __restrict__ vs) {
    __shared__ float sA[64][68];
    __shared__ float sW[64][128];
    int t = threadIdx.x;
    int tile0 = blockIdx.x * 64;
    for (int i = t; i < 2048; i += 256)
        ((float4*)sW)[i] = ((const float4*)Wcat)[i];
    for (int f = t; f < 1024; f += 256) {
        int n = f >> 4, k4 = f & 15;
        float4 v4 = (tile0 + n < N_NODES)
            ? ((const float4*)(ent + (size_t)(tile0 + n) * 64))[k4]
            : make_float4(0.f, 0.f, 0.f, 0.f);
        *(float4*)&sA[n][k4 * 4] = v4;
    }
    __syncthreads();

    int ng = t >> 4;
    int jg = t & 15;
    int n0 = ng * 4;
    int j0 = jg * 8;

    float4 d0 = *(const float4*)(dcat + j0);
    float4 d1 = *(const float4*)(dcat + j0 + 4);
    float acc[4][8];
    #pragma unroll
    for (int a = 0; a < 4; a++) {
        acc[a][0] = d0.x; acc[a][1] = d0.y; acc[a][2] = d0.z; acc[a][3] = d0.w;
        acc[a][4] = d1.x; acc[a][5] = d1.y; acc[a][6] = d1.z; acc[a][7] = d1.w;
    }

    #pragma unroll 4
    for (int k = 0; k < 64; k++) {
        float4 w0 = *(const float4*)&sW[k][j0];
        float4 w1 = *(const float4*)&sW[k][j0 + 4];
        float e0 = sA[n0][k], e1 = sA[n0+1][k], e2 = sA[n0+2][k], e3 = sA[n0+3][k];
        float e[4] = {e0, e1, e2, e3};
        #pragma unroll
        for (int a = 0; a < 4; a++) {
            acc[a][0] += e[a] * w0.x; acc[a][1] += e[a] * w0.y;
            acc[a][2] += e[a] * w0.z; acc[a][3] += e[a] * w0.w;
            acc[a][4] += e[a] * w1.x; acc[a][5] += e[a] * w1.y;
            acc[a][6] += e[a] * w1.z; acc[a][7] += e[a] * w1.w;
        }
    }

    int jw = j0 & 63;
    float4 wa0 = *(const float4*)(W_a + jw);
    float4 wa1 = *(const float4*)(W_a + jw + 4);
    float part[4];
    #pragma unroll
    for (int a = 0; a < 4; a++) {
        part[a] = acc[a][0]*wa0.x + acc[a][1]*wa0.y + acc[a][2]*wa0.z + acc[a][3]*wa0.w
                + acc[a][4]*wa1.x + acc[a][5]*wa1.y + acc[a][6]*wa1.z + acc[a][7]*wa1.w;
    }
    #pragma unroll
    for (int m = 1; m <= 4; m <<= 1) {
        #pragma unroll
        for (int a = 0; a < 4; a++) part[a] += __shfl_xor(part[a], m, 64);
    }
    if ((jg & 7) == 0) {
        float* sv = (jg < 8) ? us : vs;
        #pragma unroll
        for (int a = 0; a < 4; a++)
            if (tile0 + n0 + a < N_NODES) sv[tile0 + n0 + a] = part[a];
    }

    #pragma unroll
    for (int a = 0; a < 4; a++) {
        int n = tile0 + n0 + a;
        if (n >= N_NODES) break;
        float4 o0 = make_float4(acc[a][0], acc[a][1], acc[a][2], acc[a][3]);
        float4 o1 = make_float4(acc[a][4], acc[a][5], acc[a][6], acc[a][7]);
        float* base = (jg < 8) ? (Uout + (size_t)n * 64 + j0) : (V + (size_t)n * 64 + (j0 - 64));
        *(float4*)(base) = o0;
        *(float4*)(base + 4) = o1;
    }
}

// K2: per-relation projections.
__global__ __launch_bounds__(256, 2) void k_relproj(const float* __restrict__ relE,
        const float* __restrict__ MW, const float* __restrict__ MQ,
        const float* __restrict__ dW, const float* __restrict__ dQ,
        const float* __restrict__ W_a,
        float* __restrict__ Wr, float* __restrict__ Qr, float* __restrict__ wsr) {
    int lane = threadIdx.x & 63;
    int wv = threadIdx.x >> 6;
    float mw[64], mq[64];
    #pragma unroll
    for (int i = 0; i < 64; i++) { mw[i] = MW[lane*64 + i]; mq[i] = MQ[lane*64 + i]; }
    float dw = dW[lane], dq = dQ[lane], wa = W_a[lane];
    int r = blockIdx.x * 4 + wv;
    if (r >= N_RELS) return;
    float e = relE[(size_t)r * 64 + lane];
    float w = dw, q = dq;
    #pragma unroll
    for (int i = 0; i < 64; i++) {
        float ei = __shfl(e, i, 64);
        w += ei * mw[i];
        q += ei * mq[i];
    }
    Wr[(size_t)r * 64 + lane] = w;
    Qr[(size_t)r * 64 + lane] = q;
    float tw = w * wa;
    #pragma unroll
    for (int o = 32; o; o >>= 1) tw += __shfl_xor(tw, o, 64);
    if (lane == 0) wsr[r] = tw;
}

__global__ void k_zero(int* __restrict__ a, int n) {
    int g = blockIdx.x * 256 + threadIdx.x;
    if (g < n) a[g] = 0;
}

// ---------------------------------------------------------------------------
// K3: histogram. 2048 edges/block, 8 edges/thread, batched atomics.
// blkhist stored TRANSPOSED: blkhist[r * NB_E + b] so the scan is coalesced
// per relation (one wave scans a contiguous row).
// ---------------------------------------------------------------------------
__global__ __launch_bounds__(256) void k_hist(const int* __restrict__ src, const int* __restrict__ rel,
        int* __restrict__ cnt_src, int* __restrict__ cnt_rel, int* __restrict__ blkhist) {
    __shared__ int lcnt[N_RELS];
    int t = threadIdx.x;
    for (int r = t; r < N_RELS; r += 256) lcnt[r] = 0;
    __syncthreads();
    int base = blockIdx.x * SC_EDGES;
    if (base + SC_EDGES <= N_EDGES) {
        int e0 = base + t * 8;
        int4 sa = *(const int4*)(src + e0);
        int4 sb = *(const int4*)(src + e0 + 4);
        int4 ra = *(const int4*)(rel + e0);
        int4 rb = *(const int4*)(rel + e0 + 4);
        atomicAdd(&cnt_src[sa.x], 1); atomicAdd(&cnt_src[sa.y], 1);
        atomicAdd(&cnt_src[sa.z], 1); atomicAdd(&cnt_src[sa.w], 1);
        atomicAdd(&cnt_src[sb.x], 1); atomicAdd(&cnt_src[sb.y], 1);
        atomicAdd(&cnt_src[sb.z], 1); atomicAdd(&cnt_src[sb.w], 1);
        atomicAdd(&lcnt[ra.x], 1); atomicAdd(&lcnt[ra.y], 1);
        atomicAdd(&lcnt[ra.z], 1); atomicAdd(&lcnt[ra.w], 1);
        atomicAdd(&lcnt[rb.x], 1); atomicAdd(&lcnt[rb.y], 1);
        atomicAdd(&lcnt[rb.z], 1); atomicAdd(&lcnt[rb.w], 1);
    } else {
        for (int g = base + t; g < N_EDGES; g += 256) {
            atomicAdd(&cnt_src[src[g]], 1);
            atomicAdd(&lcnt[rel[g]], 1);
        }
    }
    __syncthreads();
    for (int r = t; r < N_RELS; r += 256) {
        int c = lcnt[r];
        blkhist[(size_t)r * NB_E + blockIdx.x] = c;
        if (c) atomicAdd(&cnt_rel[r], c);
    }
}

// exclusive scan of cnt over chunks of 1024; partials[b] = chunk total
__global__ void k_scan_local(const int* __restrict__ cnt, int* __restrict__ start,
                             int* __restrict__ partials, int n) {
    __shared__ int tot[256];
    int base = blockIdx.x * 1024;
    int t = threadIdx.x;
    int myv[4];
    int mySum = 0;
    for (int q = 0; q < 4; q++) {
        int g = base + t * 4 + q;
        int v = (g < n) ? cnt[g] : 0;
        myv[q] = v; mySum += v;
    }
    tot[t] = mySum;
    __syncthreads();
    for (int o = 1; o < 256; o <<= 1) {
        int v = (t >= o) ? tot[t - o] : 0;
        __syncthreads();
        tot[t] += v;
        __syncthreads();
    }
    int run = tot[t] - mySum;
    for (int q = 0; q < 4; q++) {
        int g = base + t * 4 + q;
        if (g < n) start[g] = run;
        run += myv[q];
    }
    if (t == 255) partials[blockIdx.x] = tot[255];
}

__global__ void k_scan_part(int* __restrict__ partials, int n) {
    __shared__ int s[256];
    int t = threadIdx.x;
    int v = (t < n) ? partials[t] : 0;
    s[t] = v;
    __syncthreads();
    for (int o = 1; o < 256; o <<= 1) {
        int u = (t >= o) ? s[t - o] : 0;
        __syncthreads();
        s[t] += u;
        __syncthreads();
    }
    if (t < n) partials[t] = s[t] - v;
}

__global__ void k_scan_add(int* __restrict__ start, const int* __restrict__ partials,
                           int* __restrict__ ctr, int n) {
    int g = blockIdx.x * 256 + threadIdx.x;
    if (g < n) {
        int v = start[g] + partials[g >> 10];
        start[g] = v;
        ctr[g] = v;
    }
}

__global__ void k_scan_small(const int* __restrict__ cnt, int* __restrict__ start, int n) {
    __shared__ int tot[256];
    int t = threadIdx.x;
    int myv[4];
    int mySum = 0;
    for (int q = 0; q < 4; q++) {
        int g = t * 4 + q;
        int v = (g < n) ? cnt[g] : 0;
        myv[q] = v; mySum += v;
    }
    tot[t] = mySum;
    __syncthreads();
    for (int o = 1; o < 256; o <<= 1) {
        int u = (t >= o) ? tot[t - o] : 0;
        __syncthreads();
        tot[t] += u;
        __syncthreads();
    }
    int run = tot[t] - mySum;
    for (int q = 0; q < 4; q++) {
        int g = t * 4 + q;
        if (g < n) start[g] = run;
        run += myv[q];
    }
}

// ---------------------------------------------------------------------------
// K4: per-(rel, block) bases. One WAVE per relation scanning its contiguous
// transposed row: coalesced 64-wide loads + wave shfl prefix scan.
// ---------------------------------------------------------------------------
__global__ __launch_bounds__(256) void k_scan_relblk(const int* __restrict__ start_rel,
        const int* __restrict__ blkhist, int* __restrict__ blkbase) {
    int lane = threadIdx.x & 63;
    int r = (blockIdx.x * 256 + threadIdx.x) >> 6;
    if (r >= N_RELS) return;
    int run = start_rel[r];
    for (int base = 0; base < NB_E; base += 64) {
        int b = base + lane;
        int v = (b < NB_E) ? blkhist[(size_t)r * NB_E + b] : 0;
        int x = v;
        #pragma unroll
        for (int o = 1; o < 64; o <<= 1) {
            int y = __shfl_up(x, o, 64);
            if (lane >= o) x += y;
        }
        if (b < NB_E) blkbase[(size_t)r * NB_E + b] = run + (x - v);
        run += __shfl(x, 63, 64);
    }
}

// ---------------------------------------------------------------------------
// K5: scatter payloads. 2048 edges/block, 8 edges/thread, batched atomics.
// ---------------------------------------------------------------------------
__global__ __launch_bounds__(256) void k_scatter(const int* __restrict__ src, const int* __restrict__ dst,
        const int* __restrict__ rel, int* __restrict__ ctr_src,
        const int* __restrict__ blkbase, int2* __restrict__ pay_src, int2* __restrict__ pay_rel) {
    __shared__ int lbase[N_RELS];
    __shared__ int loff[N_RELS];
    int t = threadIdx.x;
    for (int r = t; r < N_RELS; r += 256) {
        lbase[r] = blkbase[(size_t)r * NB_E + blockIdx.x];
        loff[r] = 0;
    }
    __syncthreads();
    int base = blockIdx.x * SC_EDGES;
    if (base + SC_EDGES <= N_EDGES) {
        int e0 = base + t * 8;
        int4 sa = *(const int4*)(src + e0);
        int4 sb = *(const int4*)(src + e0 + 4);
        int4 da = *(const int4*)(dst + e0);
        int4 db = *(const int4*)(dst + e0 + 4);
        int4 ra = *(const int4*)(rel + e0);
        int4 rb = *(const int4*)(rel + e0 + 4);
        int s[8] = {sa.x, sa.y, sa.z, sa.w, sb.x, sb.y, sb.z, sb.w};
        int d[8] = {da.x, da.y, da.z, da.w, db.x, db.y, db.z, db.w};
        int r8[8] = {ra.x, ra.y, ra.z, ra.w, rb.x, rb.y, rb.z, rb.w};
        int p[8], q[8];
        #pragma unroll
        for (int j = 0; j < 8; j++) p[j] = atomicAdd(&ctr_src[s[j]], 1);
        #pragma unroll
        for (int j = 0; j < 8; j++) q[j] = lbase[r8[j]] + atomicAdd(&loff[r8[j]], 1);
        #pragma unroll
        for (int j = 0; j < 8; j++) pay_src[p[j]] = make_int2(d[j], r8[j]);
        #pragma unroll
        for (int j = 0; j < 8; j++) pay_rel[q[j]] = make_int2(s[j], d[j]);
    } else {
        for (int g = base + t; g < N_EDGES; g += 256) {
            int s = src[g], d = dst[g], r = rel[g];
            int p = atomicAdd(&ctr_src[s], 1);
            pay_src[p] = make_int2(d, r);
            int q = lbase[r] + atomicAdd(&loff[r], 1);
            pay_rel[q] = make_int2(s, d);
        }
    }
}

// ---------------------------------------------------------------------------
// K6: fused scatter-softmax + neighbor aggregation. Wave per source node.
// Fast path: 8-edge groups; lane = (edge slot 0..7) x (dim octet 0..7);
// 2 float4 V loads + 2 float4 Wr loads per lane per group (4-deep gather ILP).
// ---------------------------------------------------------------------------
__global__ __launch_bounds__(256) void k_attn(const int2* __restrict__ pay,
        const int* __restrict__ start_src, const int* __restrict__ cnt_src,
        const float* __restrict__ us, const float* __restrict__ vs,
        const float* __restrict__ wsr, const float* __restrict__ V,
        const float* __restrict__ Wr, const float* __restrict__ b_a_p,
        float* __restrict__ h) {
    int lane = threadIdx.x & 63;
    int wv = threadIdx.x >> 6;
    int n = blockIdx.x * 4 + wv;
    if (n >= N_NODES) return;
    int st = start_src[n];
    int cnt = cnt_src[n];
    if (cnt == 0) { h[(size_t)n * 64 + lane] = 0.f; return; }
    float ba = b_a_p[0];
    float usn = us[n];

    if (cnt <= 64) {
        int2 pe = (lane < cnt) ? pay[st + lane] : make_int2(0, 0);
        float bexp = 0.f;
        if (lane < cnt) {
            float s = usn + vs[pe.x] + wsr[pe.y] + ba;
            s = s > 0.f ? s : SLOPE * s;
            bexp = expf(s);
        }
        float bp = bexp;
        #pragma unroll
        for (int o = 32; o; o >>= 1) bp += __shfl_xor(bp, o, 64);
        float inv = 1.f / bp;
        int sub = lane >> 3;     // 0..7: edge slot
        int li = lane & 7;       // 0..7: dim octet
        float4 a0 = make_float4(0.f, 0.f, 0.f, 0.f);
        float4 a1 = make_float4(0.f, 0.f, 0.f, 0.f);
        int groups = (cnt + 7) >> 3;
        for (int g = 0; g < groups; g++) {
            int esel = 8 * g + sub;                 // < 64 always
            float be = __shfl(bexp, esel, 64);      // 0 for invalid edges
            int de = __shfl(pe.x, esel, 64);
            int re = __shfl(pe.y, esel, 64);
            const float* vb = V + (size_t)de * 64 + li * 8;
            const float* wb = Wr + (size_t)re * 64 + li * 8;
            float4 v0 = *(const float4*)vb;
            float4 v1 = *(const float4*)(vb + 4);
            float4 w0 = *(const float4*)wb;
            float4 w1 = *(const float4*)(wb + 4);
            a0.x += be * (v0.x + w0.x); a0.y += be * (v0.y + w0.y);
            a0.z += be * (v0.z + w0.z); a0.w += be * (v0.w + w0.w);
            a1.x += be * (v1.x + w1.x); a1.y += be * (v1.y + w1.y);
            a1.z += be * (v1.z + w1.z); a1.w += be * (v1.w + w1.w);
        }
        // reduce over the 8 edge slots (lanes l, l^8, l^16, l^32)
        #pragma unroll
        for (int m = 8; m <= 32; m <<= 1) {
            a0.x += __shfl_xor(a0.x, m, 64); a0.y += __shfl_xor(a0.y, m, 64);
            a0.z += __shfl_xor(a0.z, m, 64); a0.w += __shfl_xor(a0.w, m, 64);
            a1.x += __shfl_xor(a1.x, m, 64); a1.y += __shfl_xor(a1.y, m, 64);
            a1.z += __shfl_xor(a1.z, m, 64); a1.w += __shfl_xor(a1.w, m, 64);
        }
        if (lane < 8) {
            float* hp = h + (size_t)n * 64 + lane * 8;
            float4 u0 = *(const float4*)hp;
            float4 u1 = *(const float4*)(hp + 4);
            float4 o0 = make_float4(u0.x + a0.x * inv, u0.y + a0.y * inv,
                                    u0.z + a0.z * inv, u0.w + a0.w * inv);
            float4 o1 = make_float4(u1.x + a1.x * inv, u1.y + a1.y * inv,
                                    u1.z + a1.z * inv, u1.w + a1.w * inv);
            *(float4*)hp = o0;
            *(float4*)(hp + 4) = o1;
        }
        return;
    }

    // fallback: scalar two-pass (cnt > 64)
    float bp = 0.f;
    for (int k = lane; k < cnt; k += 64) {
        int2 p = pay[st + k];
        float s = usn + vs[p.x] + wsr[p.y] + ba;
        s = s > 0.f ? s : SLOPE * s;
        bp += expf(s);
    }
    #pragma unroll
    for (int o = 32; o; o >>= 1) bp += __shfl_xor(bp, o, 64);
    float inv = 1.f / bp;
    float acc = 0.f;
    for (int k = 0; k < cnt; k++) {
        int2 p = pay[st + k];
        float s = usn + vs[p.x] + wsr[p.y] + ba;
        s = s > 0.f ? s : SLOPE * s;
        float b = expf(s);
        acc += b * (V[(size_t)p.x * 64 + lane] + Wr[(size_t)p.y * 64 + lane]);
    }
    float u = h[(size_t)n * 64 + lane];
    h[(size_t)n * 64 + lane] = u + acc * inv;
}

// ---------------------------------------------------------------------------
// K7: relation pooling. 16 edges / block-iteration: each thread issues TWO
// independent float4 h gathers (2x MLP) + prefetched pay; LDS tree reduce.
// ---------------------------------------------------------------------------
__global__ __launch_bounds__(256) void k_relpool(const int2* __restrict__ pay,
        const int* __restrict__ start_rel, const int* __restrict__ cnt_rel,
        const float* __restrict__ h, float* __restrict__ acc_rel) {
    int r = blockIdx.x / RSUB;
    int sub = blockIdx.x % RSUB;
    int st = start_rel[r];
    int cnt = cnt_rel[r];
    int t = threadIdx.x;
    int j = t >> 5;          // 0..7 edge slot
    int side = (t >> 4) & 1; // 0=src, 1=dst
    int li = t & 15;         // float4 slot within row

    int chunk = (cnt + RSUB - 1) / RSUB;
    int k0 = sub * chunk;
    int k1 = min(k0 + chunk, cnt);
    int len = k1 - k0;

    float4 acc = make_float4(0.f, 0.f, 0.f, 0.f);
    if (len > 0) {
        int steps = (len + 15) >> 4;
        int mA = j, mB = j + 8;
        bool vA = mA < len, vB = mB < len;
        int2 pA = vA ? pay[st + k0 + mA] : make_int2(0, 0);
        int2 pB = vB ? pay[st + k0 + mB] : make_int2(0, 0);
        for (int it = 0; it < steps; it++) {
            int nA = mA + 16, nB = mB + 16;
            bool wA = (it + 1 < steps) && (nA < len);
            bool wB = (it + 1 < steps) && (nB < len);
            int2 qA = wA ? pay[st + k0 + nA] : make_int2(0, 0);
            int2 qB = wB ? pay[st + k0 + nB] : make_int2(0, 0);
            int idxA = side ? pA.y : pA.x;
            int idxB = side ? pB.y : pB.x;
            float4 hA = *(const float4*)(h + (size_t)idxA * 64 + li * 4);
            float4 hB = *(const float4*)(h + (size_t)idxB * 64 + li * 4);
            if (vA) { acc.x += hA.x; acc.y += hA.y; acc.z += hA.z; acc.w += hA.w; }
            if (vB) { acc.x += hB.x; acc.y += hB.y; acc.z += hB.z; acc.w += hB.w; }
            pA = qA; pB = qB; mA = nA; mB = nB; vA = wA; vB = wB;
        }
    }
    __shared__ float4 red[256];
    red[t] = acc;
    __syncthreads();
    if (t < 128) {
        float4 a = red[t], b = red[t + 128];
        a.x += b.x; a.y += b.y; a.z += b.z; a.w += b.w;
        red[t] = a;
    }
    __syncthreads();
    if (t < 64) {
        float4 a = red[t], b = red[t + 64];
        a.x += b.x; a.y += b.y; a.z += b.z; a.w += b.w;
        red[t] = a;
    }
    __syncthreads();
    if (t < 32) {
        float4 a = red[t], b = red[t + 32];
        a.x += b.x; a.y += b.y; a.z += b.z; a.w += b.w;
        float* dstp = &acc_rel[r * 128 + side * 64 + li * 4];
        atomicAdd(dstp + 0, a.x);
        atomicAdd(dstp + 1, a.y);
        atomicAdd(dstp + 2, a.z);
        atomicAdd(dstp + 3, a.w);
    }
}

// K8: mean + h_rel = mean @ W_rel3.T + b_rel3
__global__ void k_relfin(const float* __restrict__ acc_rel, const int* __restrict__ cnt_rel,
                         const float* __restrict__ Qr, const float* __restrict__ W_rel3,
                         const float* __restrict__ b_rel3, float* __restrict__ out) {
    int g = blockIdx.x * 256 + threadIdx.x;
    if (g >= N_RELS * 64) return;
    int r = g >> 6;
    int j = g & 63;
    int cnt = cnt_rel[r];
    float invc = 1.f / (float)(cnt > 0 ? cnt : 1);
    float s = b_rel3[j];
    for (int k = 0; k < 128; k++) s += acc_rel[r * 128 + k] * invc * W_rel3[j * 192 + k];
    if (cnt > 0)
        for (int k = 0; k < 64; k++) s += Qr[r * 64 + k] * W_rel3[j * 192 + 128 + k];
    out[g] = s;
}

extern "C" void kernel_launch(void* const* d_in, const int* in_sizes, int n_in,
                              void* d_out, int out_size, void* d_ws, size_t ws_size,
                              hipStream_t stream) {
    const float* ent    = (const float*)d_in[0];
    const float* relE   = (const float*)d_in[1];
    const float* W_ent  = (const float*)d_in[2];
    const float* b_ent  = (const float*)d_in[3];
    const float* W_relL = (const float*)d_in[4];
    const float* b_relL = (const float*)d_in[5];
    const float* W_rel2 = (const float*)d_in[6];
    const float* b_rel2 = (const float*)d_in[7];
    const float* W_rel3 = (const float*)d_in[8];
    const float* b_rel3 = (const float*)d_in[9];
    const float* W_a    = (const float*)d_in[10];
    const float* b_a    = (const float*)d_in[11];
    const float* W_fc   = (const float*)d_in[12];
    const float* b_fc   = (const float*)d_in[13];
    const int* src = (const int*)d_in[14];
    const int* dst = (const int*)d_in[15];
    const int* rel = (const int*)d_in[16];
    float* out = (float*)d_out;

    char* ws = (char*)d_ws;
    size_t off = 0;
    auto alloc = [&](size_t bytes) -> void* {
        void* p = ws + off;
        off += (bytes + 255) & ~(size_t)255;
        return p;
    };
    float* Wcat = (float*)alloc(8192 * 4);
    float* dcat = (float*)alloc(128 * 4);
    float* MW  = (float*)alloc(4096 * 4);
    float* MQ  = (float*)alloc(4096 * 4);
    float* dW  = (float*)alloc(64 * 4);
    float* dQ  = (float*)alloc(64 * 4);
    float* V   = (float*)alloc((size_t)N_NODES * 64 * 4);
    float* us  = (float*)alloc((size_t)N_NODES * 4);
    float* vs  = (float*)alloc((size_t)N_NODES * 4);
    float* Wr  = (float*)alloc((size_t)N_RELS * 64 * 4);
    float* Qr  = (float*)alloc((size_t)N_RELS * 64 * 4);
    float* wsr = (float*)alloc((size_t)N_RELS * 4);
    int* cnt_src   = (int*)alloc((size_t)N_NODES * 4);
    int* start_src = (int*)alloc((size_t)N_NODES * 4);
    int* ctr_src   = (int*)alloc((size_t)N_NODES * 4);
    int* partials  = (int*)alloc(256 * 4);
    int* cnt_rel   = (int*)alloc((size_t)N_RELS * 4);
    int* start_rel = (int*)alloc((size_t)N_RELS * 4);
    int* blkhist   = (int*)alloc((size_t)NB_E * N_RELS * 4);
    int* blkbase   = (int*)alloc((size_t)NB_E * N_RELS * 4);
    int2* pay_src  = (int2*)alloc((size_t)N_EDGES * 8);
    int2* pay_rel  = (int2*)alloc((size_t)N_EDGES * 8);
    float* acc_rel = (float*)alloc((size_t)N_RELS * 128 * 4);

    k_zero<<<(N_NODES + 255) / 256, 256, 0, stream>>>(cnt_src, N_NODES);
    k_zero<<<(N_RELS + 255) / 256, 256, 0, stream>>>(cnt_rel, N_RELS);
    k_zero<<<(N_RELS * 128 + 255) / 256, 256, 0, stream>>>((int*)acc_rel, N_RELS * 128);

    k_fold<<<65, 256, 0, stream>>>(W_ent, b_ent, W_relL, b_relL, W_rel2, b_rel2,
                                   W_fc, b_fc, Wcat, dcat, MW, MQ, dW, dQ);
    k_node<<<(N_NODES + 63) / 64, 256, 0, stream>>>(ent, Wcat, dcat, W_a, out, V, us, vs);
    k_relproj<<<125, 256, 0, stream>>>(relE, MW, MQ, dW, dQ, W_a, Wr, Qr, wsr);
    k_hist<<<NB_E, 256, 0, stream>>>(src, rel, cnt_src, cnt_rel, blkhist);
    k_scan_local<<<98, 256, 0, stream>>>(cnt_src, start_src, partials, N_NODES);
    k_scan_part<<<1, 256, 0, stream>>>(partials, 98);
    k_scan_add<<<(N_NODES + 255) / 256, 256, 0, stream>>>(start_src, partials, ctr_src, N_NODES);
    k_scan_small<<<1, 256, 0, stream>>>(cnt_rel, start_rel, N_RELS);
    k_scan_relblk<<<125, 256, 0, stream>>>(start_rel, blkhist, blkbase);
    k_scatter<<<NB_E, 256, 0, stream>>>(src, dst, rel, ctr_src, blkbase, pay_src, pay_rel);
    k_attn<<<N_NODES / 4, 256, 0, stream>>>(pay_src, start_src, cnt_src,
                                            us, vs, wsr, V, Wr, b_a, out);
    k_relpool<<<N_RELS * RSUB, 256, 0, stream>>>(pay_rel, start_rel, cnt_rel, out, acc_rel);
    k_relfin<<<(N_RELS * 64 + 255) / 256, 256, 0, stream>>>(acc_rel, cnt_rel, Qr, W_rel3,
                                                            b_rel3, out + (size_t)N_NODES * 64);
}

// Round 7
// 337.993 us; speedup vs baseline: 1.3642x; 1.2100x over previous
//
#include <hip/hip_runtime.h>
#include <math.h>

#define N_NODES 100000
#define N_RELS  500
#define DIM     64
#define N_EDGES 1000000
#define SLOPE   0.01f
#define RSUB    16      // blocks per relation in pooling
#define SC_EDGES 2048   // edges per block in hist/scatter partition
#define NB_E    489     // ceil(N_EDGES / SC_EDGES)
#define NBKT    196     // src buckets (src >> 9, 512 nodes each)
#define BSH     9
#define NROWS   (N_RELS + NBKT)   // 696 rows in blkhist/blkbase
#define BMAX    5632    // LDS slots per bucket in k_sortb (mean 5102, sigma 71)

// ---------------------------------------------------------------------------
// K0: fold the small matrices.
// ---------------------------------------------------------------------------
__global__ void k_fold(const float* __restrict__ W_ent, const float* __restrict__ b_ent,
                       const float* __restrict__ W_relL, const float* __restrict__ b_relL,
                       const float* __restrict__ W_rel2, const float* __restrict__ b_rel2,
                       const float* __restrict__ W_fc, const float* __restrict__ b_fc,
                       float* __restrict__ Wcat, float* __restrict__ dcat,
                       float* __restrict__ MW, float* __restrict__ MQ,
                       float* __restrict__ dW, float* __restrict__ dQ) {
    int idx = blockIdx.x * 256 + threadIdx.x;
    if (idx < 8192) {
        int k = idx >> 7;
        int j2 = idx & 127;
        int jj = j2 & 63;
        int off = (j2 >> 6) * 64;
        float s = 0.f;
        for (int i = 0; i < 64; i++) s += W_fc[jj*192 + off + i] * W_ent[i*64 + k];
        Wcat[k*128 + j2] = s;
    } else if (idx < 12288) {
        int rem = idx - 8192;
        int j = rem >> 6, i = rem & 63;
        float s = 0.f;
        for (int k = 0; k < 64; k++) s += W_fc[j*192 + 128 + k] * W_relL[k*64 + i];
        MW[j*64 + i] = s;
    } else if (idx < 16384) {
        int rem = idx - 12288;
        int j = rem >> 6, i = rem & 63;
        float s = 0.f;
        for (int k = 0; k < 64; k++) s += W_rel2[j*64 + k] * W_relL[k*64 + i];
        MQ[j*64 + i] = s;
    } else if (idx < 16512) {
        int j2 = idx - 16384;
        int jj = j2 & 63;
        int off = (j2 >> 6) * 64;
        float s = 0.f;
        for (int i = 0; i < 64; i++) s += b_ent[i] * W_fc[jj*192 + off + i];
        dcat[j2] = s;
    } else if (idx < 16640) {
        int rem = idx - 16512;
        int vec = rem >> 6, j = rem & 63;
        if (vec == 0) {
            float s = b_fc[j];
            for (int k = 0; k < 64; k++) s += b_relL[k] * W_fc[j*192 + 128 + k];
            dW[j] = s;
        } else {
            float s = b_rel2[j];
            for (int k = 0; k < 64; k++) s += b_relL[k] * W_rel2[j*64 + k];
            dQ[j] = s;
        }
    }
}

// ---------------------------------------------------------------------------
// K1: per-node projections as LDS-tiled register-blocked GEMM.
// ---------------------------------------------------------------------------
__global__ __launch_bounds__(256) void k_node(const float* __restrict__ ent,
        const float* __restrict__ Wcat, const float* __restrict__ dcat,
        const float* __restrict__ W_a,
        float* __restrict__ Uout, float* __restrict__ V,
        float* __restrict__ us, float* __restrict__ vs) {
    __shared__ float sA[64][68];
    __shared__ float sW[64][128];
    int t = threadIdx.x;
    int tile0 = blockIdx.x * 64;
    for (int i = t; i < 2048; i += 256)
        ((float4*)sW)[i] = ((const float4*)Wcat)[i];
    for (int f = t; f < 1024; f += 256) {
        int n = f >> 4, k4 = f & 15;
        float4 v4 = (tile0 + n < N_NODES)
            ? ((const float4*)(ent + (size_t)(tile0 + n) * 64))[k4]
            : make_float4(0.f, 0.f, 0.f, 0.f);
        *(float4*)&sA[n][k4 * 4] = v4;
    }
    __syncthreads();

    int ng = t >> 4;
    int jg = t & 15;
    int n0 = ng * 4;
    int j0 = jg * 8;

    float4 d0 = *(const float4*)(dcat + j0);
    float4 d1 = *(const float4*)(dcat + j0 + 4);
    float acc[4][8];
    #pragma unroll
    for (int a = 0; a < 4; a++) {
        acc[a][0] = d0.x; acc[a][1] = d0.y; acc[a][2] = d0.z; acc[a][3] = d0.w;
        acc[a][4] = d1.x; acc[a][5] = d1.y; acc[a][6] = d1.z; acc[a][7] = d1.w;
    }

    #pragma unroll 4
    for (int k = 0; k < 64; k++) {
        float4 w0 = *(const float4*)&sW[k][j0];
        float4 w1 = *(const float4*)&sW[k][j0 + 4];
        float e0 = sA[n0][k], e1 = sA[n0+1][k], e2 = sA[n0+2][k], e3 = sA[n0+3][k];
        float e[4] = {e0, e1, e2, e3};
        #pragma unroll
        for (int a = 0; a < 4; a++) {
            acc[a][0] += e[a] * w0.x; acc[a][1] += e[a] * w0.y;
            acc[a][2] += e[a] * w0.z; acc[a][3] += e[a] * w0.w;
            acc[a][4] += e[a] * w1.x; acc[a][5] += e[a] * w1.y;
            acc[a][6] += e[a] * w1.z; acc[a][7] += e[a] * w1.w;
        }
    }

    int jw = j0 & 63;
    float4 wa0 = *(const float4*)(W_a + jw);
    float4 wa1 = *(const float4*)(W_a + jw + 4);
    float part[4];
    #pragma unroll
    for (int a = 0; a < 4; a++) {
        part[a] = acc[a][0]*wa0.x + acc[a][1]*wa0.y + acc[a][2]*wa0.z + acc[a][3]*wa0.w
                + acc[a][4]*wa1.x + acc[a][5]*wa1.y + acc[a][6]*wa1.z + acc[a][7]*wa1.w;
    }
    #pragma unroll
    for (int m = 1; m <= 4; m <<= 1) {
        #pragma unroll
        for (int a = 0; a < 4; a++) part[a] += __shfl_xor(part[a], m, 64);
    }
    if ((jg & 7) == 0) {
        float* sv = (jg < 8) ? us : vs;
        #pragma unroll
        for (int a = 0; a < 4; a++)
            if (tile0 + n0 + a < N_NODES) sv[tile0 + n0 + a] = part[a];
    }

    #pragma unroll
    for (int a = 0; a < 4; a++) {
        int n = tile0 + n0 + a;
        if (n >= N_NODES) break;
        float4 o0 = make_float4(acc[a][0], acc[a][1], acc[a][2], acc[a][3]);
        float4 o1 = make_float4(acc[a][4], acc[a][5], acc[a][6], acc[a][7]);
        float* base = (jg < 8) ? (Uout + (size_t)n * 64 + j0) : (V + (size_t)n * 64 + (j0 - 64));
        *(float4*)(base) = o0;
        *(float4*)(base + 4) = o1;
    }
}

// K2: per-relation projections.
__global__ __launch_bounds__(256, 2) void k_relproj(const float* __restrict__ relE,
        const float* __restrict__ MW, const float* __restrict__ MQ,
        const float* __restrict__ dW, const float* __restrict__ dQ,
        const float* __restrict__ W_a,
        float* __restrict__ Wr, float* __restrict__ Qr, float* __restrict__ wsr) {
    int lane = threadIdx.x & 63;
    int wv = threadIdx.x >> 6;
    float mw[64], mq[64];
    #pragma unroll
    for (int i = 0; i < 64; i++) { mw[i] = MW[lane*64 + i]; mq[i] = MQ[lane*64 + i]; }
    float dw = dW[lane], dq = dQ[lane], wa = W_a[lane];
    int r = blockIdx.x * 4 + wv;
    if (r >= N_RELS) return;
    float e = relE[(size_t)r * 64 + lane];
    float w = dw, q = dq;
    #pragma unroll
    for (int i = 0; i < 64; i++) {
        float ei = __shfl(e, i, 64);
        w += ei * mw[i];
        q += ei * mq[i];
    }
    Wr[(size_t)r * 64 + lane] = w;
    Qr[(size_t)r * 64 + lane] = q;
    float tw = w * wa;
    #pragma unroll
    for (int o = 32; o; o >>= 1) tw += __shfl_xor(tw, o, 64);
    if (lane == 0) wsr[r] = tw;
}

__global__ void k_zero(int* __restrict__ a, int n) {
    int g = blockIdx.x * 256 + threadIdx.x;
    if (g < n) a[g] = 0;
}

// ---------------------------------------------------------------------------
// K3: histogram. LDS hists for 500 rels + 196 src-buckets. No global per-src
// atomics (start/cnt_src come from k_sortb). Transposed blkhist rows:
// row r (rel) / row 500+sb (bucket), coalesced per-row scan downstream.
// ---------------------------------------------------------------------------
__global__ __launch_bounds__(256) void k_hist(const int* __restrict__ src, const int* __restrict__ rel,
        int* __restrict__ cnt_rel, int* __restrict__ bucket_cnt, int* __restrict__ blkhist) {
    __shared__ int lcntR[N_RELS];
    __shared__ int lcntS[NBKT];
    int t = threadIdx.x;
    for (int r = t; r < N_RELS; r += 256) lcntR[r] = 0;
    for (int b = t; b < NBKT; b += 256) lcntS[b] = 0;
    __syncthreads();
    int base = blockIdx.x * SC_EDGES;
    if (base + SC_EDGES <= N_EDGES) {
        int e0 = base + t * 8;
        int4 sa = *(const int4*)(src + e0);
        int4 sb = *(const int4*)(src + e0 + 4);
        int4 ra = *(const int4*)(rel + e0);
        int4 rb = *(const int4*)(rel + e0 + 4);
        atomicAdd(&lcntS[sa.x >> BSH], 1); atomicAdd(&lcntS[sa.y >> BSH], 1);
        atomicAdd(&lcntS[sa.z >> BSH], 1); atomicAdd(&lcntS[sa.w >> BSH], 1);
        atomicAdd(&lcntS[sb.x >> BSH], 1); atomicAdd(&lcntS[sb.y >> BSH], 1);
        atomicAdd(&lcntS[sb.z >> BSH], 1); atomicAdd(&lcntS[sb.w >> BSH], 1);
        atomicAdd(&lcntR[ra.x], 1); atomicAdd(&lcntR[ra.y], 1);
        atomicAdd(&lcntR[ra.z], 1); atomicAdd(&lcntR[ra.w], 1);
        atomicAdd(&lcntR[rb.x], 1); atomicAdd(&lcntR[rb.y], 1);
        atomicAdd(&lcntR[rb.z], 1); atomicAdd(&lcntR[rb.w], 1);
    } else {
        for (int g = base + t; g < N_EDGES; g += 256) {
            atomicAdd(&lcntS[src[g] >> BSH], 1);
            atomicAdd(&lcntR[rel[g]], 1);
        }
    }
    __syncthreads();
    for (int r = t; r < N_RELS; r += 256) {
        int c = lcntR[r];
        blkhist[(size_t)r * NB_E + blockIdx.x] = c;
        if (c) atomicAdd(&cnt_rel[r], c);
    }
    for (int b = t; b < NBKT; b += 256) {
        int c = lcntS[b];
        blkhist[(size_t)(N_RELS + b) * NB_E + blockIdx.x] = c;
        if (c) atomicAdd(&bucket_cnt[b], c);
    }
}

// ---------------------------------------------------------------------------
// K4a: two independent small exclusive scans (block 0: 500 rel counts ->
// starts[0..499]; block 1: 196 bucket counts -> starts[500..695]).
// ---------------------------------------------------------------------------
__global__ void k_scan_two(const int* __restrict__ cnt_rel, const int* __restrict__ bucket_cnt,
                           int* __restrict__ starts) {
    __shared__ int tot[256];
    int t = threadIdx.x;
    const int* cnt = blockIdx.x ? bucket_cnt : cnt_rel;
    int n = blockIdx.x ? NBKT : N_RELS;
    int* out = starts + (blockIdx.x ? N_RELS : 0);
    int myv[4];
    int mySum = 0;
    for (int q = 0; q < 4; q++) {
        int g = t * 4 + q;
        int v = (g < n) ? cnt[g] : 0;
        myv[q] = v; mySum += v;
    }
    tot[t] = mySum;
    __syncthreads();
    for (int o = 1; o < 256; o <<= 1) {
        int u = (t >= o) ? tot[t - o] : 0;
        __syncthreads();
        tot[t] += u;
        __syncthreads();
    }
    int run = tot[t] - mySum;
    for (int q = 0; q < 4; q++) {
        int g = t * 4 + q;
        if (g < n) out[g] = run;
        run += myv[q];
    }
}

// ---------------------------------------------------------------------------
// K4b: per-(row, block) bases for all 696 rows. One wave per row, coalesced
// loads + wave shfl prefix scan.
// ---------------------------------------------------------------------------
__global__ __launch_bounds__(256) void k_scan_relblk(const int* __restrict__ starts,
        const int* __restrict__ blkhist, int* __restrict__ blkbase) {
    int lane = threadIdx.x & 63;
    int row = (blockIdx.x * 256 + threadIdx.x) >> 6;
    if (row >= NROWS) return;
    int run = starts[row];
    for (int base = 0; base < NB_E; base += 64) {
        int b = base + lane;
        int v = (b < NB_E) ? blkhist[(size_t)row * NB_E + b] : 0;
        int x = v;
        #pragma unroll
        for (int o = 1; o < 64; o <<= 1) {
            int y = __shfl_up(x, o, 64);
            if (lane >= o) x += y;
        }
        if (b < NB_E) blkbase[(size_t)row * NB_E + b] = run + (x - v);
        run += __shfl(x, 63, 64);
    }
}

// ---------------------------------------------------------------------------
// K5: pass-A scatter. NO global atomics. rel side -> pay_rel (as before).
// src side -> coarse bucket staging: stg_a[p]=dst, stg_b[p]=(src&511)<<9|rel.
// Runs per bucket per block ~10 edges -> mostly-full-line writes.
// ---------------------------------------------------------------------------
__global__ __launch_bounds__(256) void k_scatter(const int* __restrict__ src, const int* __restrict__ dst,
        const int* __restrict__ rel, const int* __restrict__ blkbase,
        int2* __restrict__ pay_rel, int* __restrict__ stg_a, int* __restrict__ stg_b) {
    __shared__ int lbaseR[N_RELS];
    __shared__ int loffR[N_RELS];
    __shared__ int lbaseS[NBKT];
    __shared__ int loffS[NBKT];
    int t = threadIdx.x;
    for (int r = t; r < N_RELS; r += 256) {
        lbaseR[r] = blkbase[(size_t)r * NB_E + blockIdx.x];
        loffR[r] = 0;
    }
    for (int b = t; b < NBKT; b += 256) {
        lbaseS[b] = blkbase[(size_t)(N_RELS + b) * NB_E + blockIdx.x];
        loffS[b] = 0;
    }
    __syncthreads();
    int base = blockIdx.x * SC_EDGES;
    if (base + SC_EDGES <= N_EDGES) {
        int e0 = base + t * 8;
        int4 sa = *(const int4*)(src + e0);
        int4 sb = *(const int4*)(src + e0 + 4);
        int4 da = *(const int4*)(dst + e0);
        int4 db = *(const int4*)(dst + e0 + 4);
        int4 ra = *(const int4*)(rel + e0);
        int4 rb = *(const int4*)(rel + e0 + 4);
        int s[8] = {sa.x, sa.y, sa.z, sa.w, sb.x, sb.y, sb.z, sb.w};
        int d[8] = {da.x, da.y, da.z, da.w, db.x, db.y, db.z, db.w};
        int r8[8] = {ra.x, ra.y, ra.z, ra.w, rb.x, rb.y, rb.z, rb.w};
        int p[8], q[8];
        #pragma unroll
        for (int j = 0; j < 8; j++) q[j] = lbaseR[r8[j]] + atomicAdd(&loffR[r8[j]], 1);
        #pragma unroll
        for (int j = 0; j < 8; j++) p[j] = lbaseS[s[j] >> BSH] + atomicAdd(&loffS[s[j] >> BSH], 1);
        #pragma unroll
        for (int j = 0; j < 8; j++) pay_rel[q[j]] = make_int2(s[j], d[j]);
        #pragma unroll
        for (int j = 0; j < 8; j++) stg_a[p[j]] = d[j];
        #pragma unroll
        for (int j = 0; j < 8; j++) stg_b[p[j]] = ((s[j] & 511) << 9) | r8[j];
    } else {
        for (int g = base + t; g < N_EDGES; g += 256) {
            int s = src[g], d = dst[g], r = rel[g];
            int q = lbaseR[r] + atomicAdd(&loffR[r], 1);
            pay_rel[q] = make_int2(s, d);
            int sb2 = s >> BSH;
            int p = lbaseS[sb2] + atomicAdd(&loffS[sb2], 1);
            stg_a[p] = d;
            stg_b[p] = ((s & 511) << 9) | r;
        }
    }
}

// ---------------------------------------------------------------------------
// K5b: pass-B. One block per bucket: LDS counting sort of ~5.1k edges over
// 512 local nodes; writes pay_src COALESCED + start_src/cnt_src directly.
// Fallback to direct global scatter if bucket exceeds BMAX (never expected).
// ---------------------------------------------------------------------------
__global__ __launch_bounds__(256) void k_sortb(const int* __restrict__ stg_a,
        const int* __restrict__ stg_b, const int* __restrict__ starts,
        const int* __restrict__ bucket_cnt, int2* __restrict__ pay_src,
        int* __restrict__ start_src, int* __restrict__ cnt_src) {
    __shared__ int hist[512];
    __shared__ int lstart[512];
    __shared__ int loff[512];
    __shared__ int tot[256];
    __shared__ int2 lpay[BMAX];
    int bkt = blockIdx.x;
    int base = starts[N_RELS + bkt];
    int n = bucket_cnt[bkt];
    int t = threadIdx.x;
    hist[t] = 0; hist[t + 256] = 0;
    __syncthreads();
    for (int i = t; i < n; i += 256)
        atomicAdd(&hist[stg_b[base + i] >> 9], 1);
    __syncthreads();
    int v0 = hist[t * 2], v1 = hist[t * 2 + 1];
    int mySum = v0 + v1;
    tot[t] = mySum;
    __syncthreads();
    for (int o = 1; o < 256; o <<= 1) {
        int u = (t >= o) ? tot[t - o] : 0;
        __syncthreads();
        tot[t] += u;
        __syncthreads();
    }
    int run = tot[t] - mySum;
    lstart[t * 2] = run;
    lstart[t * 2 + 1] = run + v0;
    loff[t * 2] = 0;
    loff[t * 2 + 1] = 0;
    int node0 = bkt * 512 + t * 2;
    if (node0 < N_NODES) { start_src[node0] = base + run; cnt_src[node0] = v0; }
    if (node0 + 1 < N_NODES) { start_src[node0 + 1] = base + run + v0; cnt_src[node0 + 1] = v1; }
    __syncthreads();
    bool fits = (n <= BMAX);
    for (int i = t; i < n; i += 256) {
        int bb = stg_b[base + i];
        int d = stg_a[base + i];
        int lo = bb >> 9;
        int2 pr = make_int2(d, bb & 511);
        int pos = lstart[lo] + atomicAdd(&loff[lo], 1);
        if (fits) lpay[pos] = pr;
        else pay_src[base + pos] = pr;
    }
    __syncthreads();
    if (fits)
        for (int i = t; i < n; i += 256)
            pay_src[base + i] = lpay[i];
}

// ---------------------------------------------------------------------------
// K6: fused scatter-softmax + neighbor aggregation. Wave per source node.
// ---------------------------------------------------------------------------
__global__ __launch_bounds__(256) void k_attn(const int2* __restrict__ pay,
        const int* __restrict__ start_src, const int* __restrict__ cnt_src,
        const float* __restrict__ us, const float* __restrict__ vs,
        const float* __restrict__ wsr, const float* __restrict__ V,
        const float* __restrict__ Wr, const float* __restrict__ b_a_p,
        float* __restrict__ h) {
    int lane = threadIdx.x & 63;
    int wv = threadIdx.x >> 6;
    int n = blockIdx.x * 4 + wv;
    if (n >= N_NODES) return;
    int st = start_src[n];
    int cnt = cnt_src[n];
    if (cnt == 0) { h[(size_t)n * 64 + lane] = 0.f; return; }
    float ba = b_a_p[0];
    float usn = us[n];

    if (cnt <= 64) {
        int2 pe = (lane < cnt) ? pay[st + lane] : make_int2(0, 0);
        float bexp = 0.f;
        if (lane < cnt) {
            float s = usn + vs[pe.x] + wsr[pe.y] + ba;
            s = s > 0.f ? s : SLOPE * s;
            bexp = expf(s);
        }
        float bp = bexp;
        #pragma unroll
        for (int o = 32; o; o >>= 1) bp += __shfl_xor(bp, o, 64);
        float inv = 1.f / bp;
        int sub = lane >> 3;
        int li = lane & 7;
        float4 a0 = make_float4(0.f, 0.f, 0.f, 0.f);
        float4 a1 = make_float4(0.f, 0.f, 0.f, 0.f);
        int groups = (cnt + 7) >> 3;
        for (int g = 0; g < groups; g++) {
            int esel = 8 * g + sub;
            float be = __shfl(bexp, esel, 64);
            int de = __shfl(pe.x, esel, 64);
            int re = __shfl(pe.y, esel, 64);
            const float* vb = V + (size_t)de * 64 + li * 8;
            const float* wb = Wr + (size_t)re * 64 + li * 8;
            float4 v0 = *(const float4*)vb;
            float4 v1 = *(const float4*)(vb + 4);
            float4 w0 = *(const float4*)wb;
            float4 w1 = *(const float4*)(wb + 4);
            a0.x += be * (v0.x + w0.x); a0.y += be * (v0.y + w0.y);
            a0.z += be * (v0.z + w0.z); a0.w += be * (v0.w + w0.w);
            a1.x += be * (v1.x + w1.x); a1.y += be * (v1.y + w1.y);
            a1.z += be * (v1.z + w1.z); a1.w += be * (v1.w + w1.w);
        }
        #pragma unroll
        for (int m = 8; m <= 32; m <<= 1) {
            a0.x += __shfl_xor(a0.x, m, 64); a0.y += __shfl_xor(a0.y, m, 64);
            a0.z += __shfl_xor(a0.z, m, 64); a0.w += __shfl_xor(a0.w, m, 64);
            a1.x += __shfl_xor(a1.x, m, 64); a1.y += __shfl_xor(a1.y, m, 64);
            a1.z += __shfl_xor(a1.z, m, 64); a1.w += __shfl_xor(a1.w, m, 64);
        }
        if (lane < 8) {
            float* hp = h + (size_t)n * 64 + lane * 8;
            float4 u0 = *(const float4*)hp;
            float4 u1 = *(const float4*)(hp + 4);
            float4 o0 = make_float4(u0.x + a0.x * inv, u0.y + a0.y * inv,
                                    u0.z + a0.z * inv, u0.w + a0.w * inv);
            float4 o1 = make_float4(u1.x + a1.x * inv, u1.y + a1.y * inv,
                                    u1.z + a1.z * inv, u1.w + a1.w * inv);
            *(float4*)hp = o0;
            *(float4*)(hp + 4) = o1;
        }
        return;
    }

    float bp = 0.f;
    for (int k = lane; k < cnt; k += 64) {
        int2 p = pay[st + k];
        float s = usn + vs[p.x] + wsr[p.y] + ba;
        s = s > 0.f ? s : SLOPE * s;
        bp += expf(s);
    }
    #pragma unroll
    for (int o = 32; o; o >>= 1) bp += __shfl_xor(bp, o, 64);
    float inv = 1.f / bp;
    float acc = 0.f;
    for (int k = 0; k < cnt; k++) {
        int2 p = pay[st + k];
        float s = usn + vs[p.x] + wsr[p.y] + ba;
        s = s > 0.f ? s : SLOPE * s;
        float b = expf(s);
        acc += b * (V[(size_t)p.x * 64 + lane] + Wr[(size_t)p.y * 64 + lane]);
    }
    float u = h[(size_t)n * 64 + lane];
    h[(size_t)n * 64 + lane] = u + acc * inv;
}

// ---------------------------------------------------------------------------
// K7: relation pooling (2x float4 gather ILP, prefetched pay, LDS reduce).
// ---------------------------------------------------------------------------
__global__ __launch_bounds__(256) void k_relpool(const int2* __restrict__ pay,
        const int* __restrict__ start_rel, const int* __restrict__ cnt_rel,
        const float* __restrict__ h, float* __restrict__ acc_rel) {
    int r = blockIdx.x / RSUB;
    int sub = blockIdx.x % RSUB;
    int st = start_rel[r];
    int cnt = cnt_rel[r];
    int t = threadIdx.x;
    int j = t >> 5;
    int side = (t >> 4) & 1;
    int li = t & 15;

    int chunk = (cnt + RSUB - 1) / RSUB;
    int k0 = sub * chunk;
    int k1 = min(k0 + chunk, cnt);
    int len = k1 - k0;

    float4 acc = make_float4(0.f, 0.f, 0.f, 0.f);
    if (len > 0) {
        int steps = (len + 15) >> 4;
        int mA = j, mB = j + 8;
        bool vA = mA < len, vB = mB < len;
        int2 pA = vA ? pay[st + k0 + mA] : make_int2(0, 0);
        int2 pB = vB ? pay[st + k0 + mB] : make_int2(0, 0);
        for (int it = 0; it < steps; it++) {
            int nA = mA + 16, nB = mB + 16;
            bool wA = (it + 1 < steps) && (nA < len);
            bool wB = (it + 1 < steps) && (nB < len);
            int2 qA = wA ? pay[st + k0 + nA] : make_int2(0, 0);
            int2 qB = wB ? pay[st + k0 + nB] : make_int2(0, 0);
            int idxA = side ? pA.y : pA.x;
            int idxB = side ? pB.y : pB.x;
            float4 hA = *(const float4*)(h + (size_t)idxA * 64 + li * 4);
            float4 hB = *(const float4*)(h + (size_t)idxB * 64 + li * 4);
            if (vA) { acc.x += hA.x; acc.y += hA.y; acc.z += hA.z; acc.w += hA.w; }
            if (vB) { acc.x += hB.x; acc.y += hB.y; acc.z += hB.z; acc.w += hB.w; }
            pA = qA; pB = qB; mA = nA; mB = nB; vA = wA; vB = wB;
        }
    }
    __shared__ float4 red[256];
    red[t] = acc;
    __syncthreads();
    if (t < 128) {
        float4 a = red[t], b = red[t + 128];
        a.x += b.x; a.y += b.y; a.z += b.z; a.w += b.w;
        red[t] = a;
    }
    __syncthreads();
    if (t < 64) {
        float4 a = red[t], b = red[t + 64];
        a.x += b.x; a.y += b.y; a.z += b.z; a.w += b.w;
        red[t] = a;
    }
    __syncthreads();
    if (t < 32) {
        float4 a = red[t], b = red[t + 32];
        a.x += b.x; a.y += b.y; a.z += b.z; a.w += b.w;
        float* dstp = &acc_rel[r * 128 + side * 64 + li * 4];
        atomicAdd(dstp + 0, a.x);
        atomicAdd(dstp + 1, a.y);
        atomicAdd(dstp + 2, a.z);
        atomicAdd(dstp + 3, a.w);
    }
}

// K8: mean + h_rel = mean @ W_rel3.T + b_rel3
__global__ void k_relfin(const float* __restrict__ acc_rel, const int* __restrict__ cnt_rel,
                         const float* __restrict__ Qr, const float* __restrict__ W_rel3,
                         const float* __restrict__ b_rel3, float* __restrict__ out) {
    int g = blockIdx.x * 256 + threadIdx.x;
    if (g >= N_RELS * 64) return;
    int r = g >> 6;
    int j = g & 63;
    int cnt = cnt_rel[r];
    float invc = 1.f / (float)(cnt > 0 ? cnt : 1);
    float s = b_rel3[j];
    for (int k = 0; k < 128; k++) s += acc_rel[r * 128 + k] * invc * W_rel3[j * 192 + k];
    if (cnt > 0)
        for (int k = 0; k < 64; k++) s += Qr[r * 64 + k] * W_rel3[j * 192 + 128 + k];
    out[g] = s;
}

extern "C" void kernel_launch(void* const* d_in, const int* in_sizes, int n_in,
                              void* d_out, int out_size, void* d_ws, size_t ws_size,
                              hipStream_t stream) {
    const float* ent    = (const float*)d_in[0];
    const float* relE   = (const float*)d_in[1];
    const float* W_ent  = (const float*)d_in[2];
    const float* b_ent  = (const float*)d_in[3];
    const float* W_relL = (const float*)d_in[4];
    const float* b_relL = (const float*)d_in[5];
    const float* W_rel2 = (const float*)d_in[6];
    const float* b_rel2 = (const float*)d_in[7];
    const float* W_rel3 = (const float*)d_in[8];
    const float* b_rel3 = (const float*)d_in[9];
    const float* W_a    = (const float*)d_in[10];
    const float* b_a    = (const float*)d_in[11];
    const float* W_fc   = (const float*)d_in[12];
    const float* b_fc   = (const float*)d_in[13];
    const int* src = (const int*)d_in[14];
    const int* dst = (const int*)d_in[15];
    const int* rel = (const int*)d_in[16];
    float* out = (float*)d_out;

    char* ws = (char*)d_ws;
    size_t off = 0;
    auto alloc = [&](size_t bytes) -> void* {
        void* p = ws + off;
        off += (bytes + 255) & ~(size_t)255;
        return p;
    };
    float* Wcat = (float*)alloc(8192 * 4);
    float* dcat = (float*)alloc(128 * 4);
    float* MW  = (float*)alloc(4096 * 4);
    float* MQ  = (float*)alloc(4096 * 4);
    float* dW  = (float*)alloc(64 * 4);
    float* dQ  = (float*)alloc(64 * 4);
    float* V   = (float*)alloc((size_t)N_NODES * 64 * 4);
    float* us  = (float*)alloc((size_t)N_NODES * 4);
    float* vs  = (float*)alloc((size_t)N_NODES * 4);
    float* Wr  = (float*)alloc((size_t)N_RELS * 64 * 4);
    float* Qr  = (float*)alloc((size_t)N_RELS * 64 * 4);
    float* wsr = (float*)alloc((size_t)N_RELS * 4);
    int* cnt_src   = (int*)alloc((size_t)N_NODES * 4);
    int* start_src = (int*)alloc((size_t)N_NODES * 4);
    int* cnts      = (int*)alloc((size_t)NROWS * 4);   // [0..499]=cnt_rel, [500..695]=bucket_cnt
    int* starts    = (int*)alloc((size_t)NROWS * 4);   // same split
    int* blkhist   = (int*)alloc((size_t)NROWS * NB_E * 4);
    int* blkbase   = (int*)alloc((size_t)NROWS * NB_E * 4);
    int* stg_a     = (int*)alloc((size_t)N_EDGES * 4);
    int* stg_b     = (int*)alloc((size_t)N_EDGES * 4);
    int2* pay_src  = (int2*)alloc((size_t)N_EDGES * 8);
    int2* pay_rel  = (int2*)alloc((size_t)N_EDGES * 8);
    float* acc_rel = (float*)alloc((size_t)N_RELS * 128 * 4);

    int* cnt_rel    = cnts;
    int* bucket_cnt = cnts + N_RELS;

    k_zero<<<(NROWS + 255) / 256, 256, 0, stream>>>(cnts, NROWS);
    k_zero<<<(N_RELS * 128 + 255) / 256, 256, 0, stream>>>((int*)acc_rel, N_RELS * 128);

    k_fold<<<65, 256, 0, stream>>>(W_ent, b_ent, W_relL, b_relL, W_rel2, b_rel2,
                                   W_fc, b_fc, Wcat, dcat, MW, MQ, dW, dQ);
    k_node<<<(N_NODES + 63) / 64, 256, 0, stream>>>(ent, Wcat, dcat, W_a, out, V, us, vs);
    k_relproj<<<125, 256, 0, stream>>>(relE, MW, MQ, dW, dQ, W_a, Wr, Qr, wsr);
    k_hist<<<NB_E, 256, 0, stream>>>(src, rel, cnt_rel, bucket_cnt, blkhist);
    k_scan_two<<<2, 256, 0, stream>>>(cnt_rel, bucket_cnt, starts);
    k_scan_relblk<<<(NROWS * 64) / 256, 256, 0, stream>>>(starts, blkhist, blkbase);
    k_scatter<<<NB_E, 256, 0, stream>>>(src, dst, rel, blkbase, pay_rel, stg_a, stg_b);
    k_sortb<<<NBKT, 256, 0, stream>>>(stg_a, stg_b, starts, bucket_cnt,
                                      pay_src, start_src, cnt_src);
    k_attn<<<N_NODES / 4, 256, 0, stream>>>(pay_src, start_src, cnt_src,
                                            us, vs, wsr, V, Wr, b_a, out);
    k_relpool<<<N_RELS * RSUB, 256, 0, stream>>>(pay_rel, starts, cnt_rel, out, acc_rel);
    k_relfin<<<(N_RELS * 64 + 255) / 256, 256, 0, stream>>>(acc_rel, cnt_rel, Qr, W_rel3,
                                                            b_rel3, out + (size_t)N_NODES * 64);
}

// Round 8
// 319.431 us; speedup vs baseline: 1.4435x; 1.0581x over previous
//
#include <hip/hip_runtime.h>
#include <math.h>

#define N_NODES 100000
#define N_RELS  500
#define DIM     64
#define N_EDGES 1000000
#define SLOPE   0.01f
#define RSUB    16      // blocks per relation in pooling
#define SC_EDGES 2048   // edges per block in hist/scatter partition
#define NB_E    489     // ceil(N_EDGES / SC_EDGES)
#define NBKT    196     // src buckets (src >> 9, 512 nodes each)
#define BSH     9
#define NROWS   (N_RELS + NBKT)   // 696 rows in blkhist/blkbase
#define BMAX    5632    // LDS slots per bucket in k_sortb

// bf16 pack/unpack (round-to-nearest-even)
__device__ __forceinline__ unsigned short f2bf(float f) {
    unsigned int u = __float_as_uint(f);
    u += 0x7FFFu + ((u >> 16) & 1u);
    return (unsigned short)(u >> 16);
}
__device__ __forceinline__ float bfl(unsigned int u) { return __uint_as_float(u << 16); }
__device__ __forceinline__ float bfh(unsigned int u) { return __uint_as_float(u & 0xFFFF0000u); }

// ---------------------------------------------------------------------------
// K0: fold the small matrices.
// ---------------------------------------------------------------------------
__global__ void k_fold(const float* __restrict__ W_ent, const float* __restrict__ b_ent,
                       const float* __restrict__ W_relL, const float* __restrict__ b_relL,
                       const float* __restrict__ W_rel2, const float* __restrict__ b_rel2,
                       const float* __restrict__ W_fc, const float* __restrict__ b_fc,
                       float* __restrict__ Wcat, float* __restrict__ dcat,
                       float* __restrict__ MW, float* __restrict__ MQ,
                       float* __restrict__ dW, float* __restrict__ dQ) {
    int idx = blockIdx.x * 256 + threadIdx.x;
    if (idx < 8192) {
        int k = idx >> 7;
        int j2 = idx & 127;
        int jj = j2 & 63;
        int off = (j2 >> 6) * 64;
        float s = 0.f;
        for (int i = 0; i < 64; i++) s += W_fc[jj*192 + off + i] * W_ent[i*64 + k];
        Wcat[k*128 + j2] = s;
    } else if (idx < 12288) {
        int rem = idx - 8192;
        int j = rem >> 6, i = rem & 63;
        float s = 0.f;
        for (int k = 0; k < 64; k++) s += W_fc[j*192 + 128 + k] * W_relL[k*64 + i];
        MW[j*64 + i] = s;
    } else if (idx < 16384) {
        int rem = idx - 12288;
        int j = rem >> 6, i = rem & 63;
        float s = 0.f;
        for (int k = 0; k < 64; k++) s += W_rel2[j*64 + k] * W_relL[k*64 + i];
        MQ[j*64 + i] = s;
    } else if (idx < 16512) {
        int j2 = idx - 16384;
        int jj = j2 & 63;
        int off = (j2 >> 6) * 64;
        float s = 0.f;
        for (int i = 0; i < 64; i++) s += b_ent[i] * W_fc[jj*192 + off + i];
        dcat[j2] = s;
    } else if (idx < 16640) {
        int rem = idx - 16512;
        int vec = rem >> 6, j = rem & 63;
        if (vec == 0) {
            float s = b_fc[j];
            for (int k = 0; k < 64; k++) s += b_relL[k] * W_fc[j*192 + 128 + k];
            dW[j] = s;
        } else {
            float s = b_rel2[j];
            for (int k = 0; k < 64; k++) s += b_relL[k] * W_rel2[j*64 + k];
            dQ[j] = s;
        }
    }
}

// ---------------------------------------------------------------------------
// K1: per-node projections (LDS-tiled GEMM). U -> fp32 (output buffer);
// V -> bf16 shadow only (sole consumer is k_attn's gather).
// ---------------------------------------------------------------------------
__global__ __launch_bounds__(256) void k_node(const float* __restrict__ ent,
        const float* __restrict__ Wcat, const float* __restrict__ dcat,
        const float* __restrict__ W_a,
        float* __restrict__ Uout, unsigned short* __restrict__ V16,
        float* __restrict__ us, float* __restrict__ vs) {
    __shared__ float sA[64][68];
    __shared__ float sW[64][128];
    int t = threadIdx.x;
    int tile0 = blockIdx.x * 64;
    for (int i = t; i < 2048; i += 256)
        ((float4*)sW)[i] = ((const float4*)Wcat)[i];
    for (int f = t; f < 1024; f += 256) {
        int n = f >> 4, k4 = f & 15;
        float4 v4 = (tile0 + n < N_NODES)
            ? ((const float4*)(ent + (size_t)(tile0 + n) * 64))[k4]
            : make_float4(0.f, 0.f, 0.f, 0.f);
        *(float4*)&sA[n][k4 * 4] = v4;
    }
    __syncthreads();

    int ng = t >> 4;
    int jg = t & 15;
    int n0 = ng * 4;
    int j0 = jg * 8;

    float4 d0 = *(const float4*)(dcat + j0);
    float4 d1 = *(const float4*)(dcat + j0 + 4);
    float acc[4][8];
    #pragma unroll
    for (int a = 0; a < 4; a++) {
        acc[a][0] = d0.x; acc[a][1] = d0.y; acc[a][2] = d0.z; acc[a][3] = d0.w;
        acc[a][4] = d1.x; acc[a][5] = d1.y; acc[a][6] = d1.z; acc[a][7] = d1.w;
    }

    #pragma unroll 4
    for (int k = 0; k < 64; k++) {
        float4 w0 = *(const float4*)&sW[k][j0];
        float4 w1 = *(const float4*)&sW[k][j0 + 4];
        float e0 = sA[n0][k], e1 = sA[n0+1][k], e2 = sA[n0+2][k], e3 = sA[n0+3][k];
        float e[4] = {e0, e1, e2, e3};
        #pragma unroll
        for (int a = 0; a < 4; a++) {
            acc[a][0] += e[a] * w0.x; acc[a][1] += e[a] * w0.y;
            acc[a][2] += e[a] * w0.z; acc[a][3] += e[a] * w0.w;
            acc[a][4] += e[a] * w1.x; acc[a][5] += e[a] * w1.y;
            acc[a][6] += e[a] * w1.z; acc[a][7] += e[a] * w1.w;
        }
    }

    int jw = j0 & 63;
    float4 wa0 = *(const float4*)(W_a + jw);
    float4 wa1 = *(const float4*)(W_a + jw + 4);
    float part[4];
    #pragma unroll
    for (int a = 0; a < 4; a++) {
        part[a] = acc[a][0]*wa0.x + acc[a][1]*wa0.y + acc[a][2]*wa0.z + acc[a][3]*wa0.w
                + acc[a][4]*wa1.x + acc[a][5]*wa1.y + acc[a][6]*wa1.z + acc[a][7]*wa1.w;
    }
    #pragma unroll
    for (int m = 1; m <= 4; m <<= 1) {
        #pragma unroll
        for (int a = 0; a < 4; a++) part[a] += __shfl_xor(part[a], m, 64);
    }
    if ((jg & 7) == 0) {
        float* sv = (jg < 8) ? us : vs;
        #pragma unroll
        for (int a = 0; a < 4; a++)
            if (tile0 + n0 + a < N_NODES) sv[tile0 + n0 + a] = part[a];
    }

    #pragma unroll
    for (int a = 0; a < 4; a++) {
        int n = tile0 + n0 + a;
        if (n >= N_NODES) break;
        if (jg < 8) {
            float4 o0 = make_float4(acc[a][0], acc[a][1], acc[a][2], acc[a][3]);
            float4 o1 = make_float4(acc[a][4], acc[a][5], acc[a][6], acc[a][7]);
            float* base = Uout + (size_t)n * 64 + j0;
            *(float4*)(base) = o0;
            *(float4*)(base + 4) = o1;
        } else {
            uint4 pv;
            pv.x = (unsigned int)f2bf(acc[a][0]) | ((unsigned int)f2bf(acc[a][1]) << 16);
            pv.y = (unsigned int)f2bf(acc[a][2]) | ((unsigned int)f2bf(acc[a][3]) << 16);
            pv.z = (unsigned int)f2bf(acc[a][4]) | ((unsigned int)f2bf(acc[a][5]) << 16);
            pv.w = (unsigned int)f2bf(acc[a][6]) | ((unsigned int)f2bf(acc[a][7]) << 16);
            *(uint4*)(V16 + (size_t)n * 64 + (j0 - 64)) = pv;
        }
    }
}

// K2: per-relation projections. Wr -> bf16 shadow; Qr fp32; wsr fp32.
__global__ __launch_bounds__(256, 2) void k_relproj(const float* __restrict__ relE,
        const float* __restrict__ MW, const float* __restrict__ MQ,
        const float* __restrict__ dW, const float* __restrict__ dQ,
        const float* __restrict__ W_a,
        unsigned short* __restrict__ Wr16, float* __restrict__ Qr, float* __restrict__ wsr) {
    int lane = threadIdx.x & 63;
    int wv = threadIdx.x >> 6;
    float mw[64], mq[64];
    #pragma unroll
    for (int i = 0; i < 64; i++) { mw[i] = MW[lane*64 + i]; mq[i] = MQ[lane*64 + i]; }
    float dw = dW[lane], dq = dQ[lane], wa = W_a[lane];
    int r = blockIdx.x * 4 + wv;
    if (r >= N_RELS) return;
    float e = relE[(size_t)r * 64 + lane];
    float w = dw, q = dq;
    #pragma unroll
    for (int i = 0; i < 64; i++) {
        float ei = __shfl(e, i, 64);
        w += ei * mw[i];
        q += ei * mq[i];
    }
    Wr16[(size_t)r * 64 + lane] = f2bf(w);
    Qr[(size_t)r * 64 + lane] = q;
    float tw = w * wa;
    #pragma unroll
    for (int o = 32; o; o >>= 1) tw += __shfl_xor(tw, o, 64);
    if (lane == 0) wsr[r] = tw;
}

__global__ void k_zero(int* __restrict__ a, int n) {
    int g = blockIdx.x * 256 + threadIdx.x;
    if (g < n) a[g] = 0;
}

// ---------------------------------------------------------------------------
// K3: histogram (LDS hists: 500 rels + 196 src-buckets; transposed blkhist).
// ---------------------------------------------------------------------------
__global__ __launch_bounds__(256) void k_hist(const int* __restrict__ src, const int* __restrict__ rel,
        int* __restrict__ cnt_rel, int* __restrict__ bucket_cnt, int* __restrict__ blkhist) {
    __shared__ int lcntR[N_RELS];
    __shared__ int lcntS[NBKT];
    int t = threadIdx.x;
    for (int r = t; r < N_RELS; r += 256) lcntR[r] = 0;
    for (int b = t; b < NBKT; b += 256) lcntS[b] = 0;
    __syncthreads();
    int base = blockIdx.x * SC_EDGES;
    if (base + SC_EDGES <= N_EDGES) {
        int e0 = base + t * 8;
        int4 sa = *(const int4*)(src + e0);
        int4 sb = *(const int4*)(src + e0 + 4);
        int4 ra = *(const int4*)(rel + e0);
        int4 rb = *(const int4*)(rel + e0 + 4);
        atomicAdd(&lcntS[sa.x >> BSH], 1); atomicAdd(&lcntS[sa.y >> BSH], 1);
        atomicAdd(&lcntS[sa.z >> BSH], 1); atomicAdd(&lcntS[sa.w >> BSH], 1);
        atomicAdd(&lcntS[sb.x >> BSH], 1); atomicAdd(&lcntS[sb.y >> BSH], 1);
        atomicAdd(&lcntS[sb.z >> BSH], 1); atomicAdd(&lcntS[sb.w >> BSH], 1);
        atomicAdd(&lcntR[ra.x], 1); atomicAdd(&lcntR[ra.y], 1);
        atomicAdd(&lcntR[ra.z], 1); atomicAdd(&lcntR[ra.w], 1);
        atomicAdd(&lcntR[rb.x], 1); atomicAdd(&lcntR[rb.y], 1);
        atomicAdd(&lcntR[rb.z], 1); atomicAdd(&lcntR[rb.w], 1);
    } else {
        for (int g = base + t; g < N_EDGES; g += 256) {
            atomicAdd(&lcntS[src[g] >> BSH], 1);
            atomicAdd(&lcntR[rel[g]], 1);
        }
    }
    __syncthreads();
    for (int r = t; r < N_RELS; r += 256) {
        int c = lcntR[r];
        blkhist[(size_t)r * NB_E + blockIdx.x] = c;
        if (c) atomicAdd(&cnt_rel[r], c);
    }
    for (int b = t; b < NBKT; b += 256) {
        int c = lcntS[b];
        blkhist[(size_t)(N_RELS + b) * NB_E + blockIdx.x] = c;
        if (c) atomicAdd(&bucket_cnt[b], c);
    }
}

// K4a: two small exclusive scans (rels, buckets).
__global__ void k_scan_two(const int* __restrict__ cnt_rel, const int* __restrict__ bucket_cnt,
                           int* __restrict__ starts) {
    __shared__ int tot[256];
    int t = threadIdx.x;
    const int* cnt = blockIdx.x ? bucket_cnt : cnt_rel;
    int n = blockIdx.x ? NBKT : N_RELS;
    int* out = starts + (blockIdx.x ? N_RELS : 0);
    int myv[4];
    int mySum = 0;
    for (int q = 0; q < 4; q++) {
        int g = t * 4 + q;
        int v = (g < n) ? cnt[g] : 0;
        myv[q] = v; mySum += v;
    }
    tot[t] = mySum;
    __syncthreads();
    for (int o = 1; o < 256; o <<= 1) {
        int u = (t >= o) ? tot[t - o] : 0;
        __syncthreads();
        tot[t] += u;
        __syncthreads();
    }
    int run = tot[t] - mySum;
    for (int q = 0; q < 4; q++) {
        int g = t * 4 + q;
        if (g < n) out[g] = run;
        run += myv[q];
    }
}

// K4b: per-(row, block) bases; one wave per row.
__global__ __launch_bounds__(256) void k_scan_relblk(const int* __restrict__ starts,
        const int* __restrict__ blkhist, int* __restrict__ blkbase) {
    int lane = threadIdx.x & 63;
    int row = (blockIdx.x * 256 + threadIdx.x) >> 6;
    if (row >= NROWS) return;
    int run = starts[row];
    for (int base = 0; base < NB_E; base += 64) {
        int b = base + lane;
        int v = (b < NB_E) ? blkhist[(size_t)row * NB_E + b] : 0;
        int x = v;
        #pragma unroll
        for (int o = 1; o < 64; o <<= 1) {
            int y = __shfl_up(x, o, 64);
            if (lane >= o) x += y;
        }
        if (b < NB_E) blkbase[(size_t)row * NB_E + b] = run + (x - v);
        run += __shfl(x, 63, 64);
    }
}

// ---------------------------------------------------------------------------
// K5: pass-A scatter (no global atomics).
// ---------------------------------------------------------------------------
__global__ __launch_bounds__(256) void k_scatter(const int* __restrict__ src, const int* __restrict__ dst,
        const int* __restrict__ rel, const int* __restrict__ blkbase,
        int2* __restrict__ pay_rel, int* __restrict__ stg_a, int* __restrict__ stg_b) {
    __shared__ int lbaseR[N_RELS];
    __shared__ int loffR[N_RELS];
    __shared__ int lbaseS[NBKT];
    __shared__ int loffS[NBKT];
    int t = threadIdx.x;
    for (int r = t; r < N_RELS; r += 256) {
        lbaseR[r] = blkbase[(size_t)r * NB_E + blockIdx.x];
        loffR[r] = 0;
    }
    for (int b = t; b < NBKT; b += 256) {
        lbaseS[b] = blkbase[(size_t)(N_RELS + b) * NB_E + blockIdx.x];
        loffS[b] = 0;
    }
    __syncthreads();
    int base = blockIdx.x * SC_EDGES;
    if (base + SC_EDGES <= N_EDGES) {
        int e0 = base + t * 8;
        int4 sa = *(const int4*)(src + e0);
        int4 sb = *(const int4*)(src + e0 + 4);
        int4 da = *(const int4*)(dst + e0);
        int4 db = *(const int4*)(dst + e0 + 4);
        int4 ra = *(const int4*)(rel + e0);
        int4 rb = *(const int4*)(rel + e0 + 4);
        int s[8] = {sa.x, sa.y, sa.z, sa.w, sb.x, sb.y, sb.z, sb.w};
        int d[8] = {da.x, da.y, da.z, da.w, db.x, db.y, db.z, db.w};
        int r8[8] = {ra.x, ra.y, ra.z, ra.w, rb.x, rb.y, rb.z, rb.w};
        int p[8], q[8];
        #pragma unroll
        for (int j = 0; j < 8; j++) q[j] = lbaseR[r8[j]] + atomicAdd(&loffR[r8[j]], 1);
        #pragma unroll
        for (int j = 0; j < 8; j++) p[j] = lbaseS[s[j] >> BSH] + atomicAdd(&loffS[s[j] >> BSH], 1);
        #pragma unroll
        for (int j = 0; j < 8; j++) pay_rel[q[j]] = make_int2(s[j], d[j]);
        #pragma unroll
        for (int j = 0; j < 8; j++) stg_a[p[j]] = d[j];
        #pragma unroll
        for (int j = 0; j < 8; j++) stg_b[p[j]] = ((s[j] & 511) << 9) | r8[j];
    } else {
        for (int g = base + t; g < N_EDGES; g += 256) {
            int s = src[g], d = dst[g], r = rel[g];
            int q = lbaseR[r] + atomicAdd(&loffR[r], 1);
            pay_rel[q] = make_int2(s, d);
            int sb2 = s >> BSH;
            int p = lbaseS[sb2] + atomicAdd(&loffS[sb2], 1);
            stg_a[p] = d;
            stg_b[p] = ((s & 511) << 9) | r;
        }
    }
}

// ---------------------------------------------------------------------------
// K5b: pass-B bucket counting sort -> pay_src + start/cnt_src.
// ---------------------------------------------------------------------------
__global__ __launch_bounds__(256) void k_sortb(const int* __restrict__ stg_a,
        const int* __restrict__ stg_b, const int* __restrict__ starts,
        const int* __restrict__ bucket_cnt, int2* __restrict__ pay_src,
        int* __restrict__ start_src, int* __restrict__ cnt_src) {
    __shared__ int hist[512];
    __shared__ int lstart[512];
    __shared__ int loff[512];
    __shared__ int tot[256];
    __shared__ int2 lpay[BMAX];
    int bkt = blockIdx.x;
    int base = starts[N_RELS + bkt];
    int n = bucket_cnt[bkt];
    int t = threadIdx.x;
    hist[t] = 0; hist[t + 256] = 0;
    __syncthreads();
    for (int i = t; i < n; i += 256)
        atomicAdd(&hist[stg_b[base + i] >> 9], 1);
    __syncthreads();
    int v0 = hist[t * 2], v1 = hist[t * 2 + 1];
    int mySum = v0 + v1;
    tot[t] = mySum;
    __syncthreads();
    for (int o = 1; o < 256; o <<= 1) {
        int u = (t >= o) ? tot[t - o] : 0;
        __syncthreads();
        tot[t] += u;
        __syncthreads();
    }
    int run = tot[t] - mySum;
    lstart[t * 2] = run;
    lstart[t * 2 + 1] = run + v0;
    loff[t * 2] = 0;
    loff[t * 2 + 1] = 0;
    int node0 = bkt * 512 + t * 2;
    if (node0 < N_NODES) { start_src[node0] = base + run; cnt_src[node0] = v0; }
    if (node0 + 1 < N_NODES) { start_src[node0 + 1] = base + run + v0; cnt_src[node0 + 1] = v1; }
    __syncthreads();
    bool fits = (n <= BMAX);
    for (int i = t; i < n; i += 256) {
        int bb = stg_b[base + i];
        int d = stg_a[base + i];
        int lo = bb >> 9;
        int2 pr = make_int2(d, bb & 511);
        int pos = lstart[lo] + atomicAdd(&loff[lo], 1);
        if (fits) lpay[pos] = pr;
        else pay_src[base + pos] = pr;
    }
    __syncthreads();
    if (fits)
        for (int i = t; i < n; i += 256)
            pay_src[base + i] = lpay[i];
}

// ---------------------------------------------------------------------------
// K6: fused scatter-softmax + aggregation. bf16 V/Wr gathers (128 B rows);
// writes h (fp32 output) + h16 shadow for the pooling kernel.
// ---------------------------------------------------------------------------
__global__ __launch_bounds__(256) void k_attn(const int2* __restrict__ pay,
        const int* __restrict__ start_src, const int* __restrict__ cnt_src,
        const float* __restrict__ us, const float* __restrict__ vs,
        const float* __restrict__ wsr, const unsigned short* __restrict__ V16,
        const unsigned short* __restrict__ Wr16, const float* __restrict__ b_a_p,
        float* __restrict__ h, unsigned short* __restrict__ h16) {
    int lane = threadIdx.x & 63;
    int wv = threadIdx.x >> 6;
    int n = blockIdx.x * 4 + wv;
    if (n >= N_NODES) return;
    int st = start_src[n];
    int cnt = cnt_src[n];
    if (cnt == 0) {
        h[(size_t)n * 64 + lane] = 0.f;
        if (lane < 8) *(uint4*)(h16 + (size_t)n * 64 + lane * 8) = make_uint4(0,0,0,0);
        return;
    }
    float ba = b_a_p[0];
    float usn = us[n];

    if (cnt <= 64) {
        int2 pe = (lane < cnt) ? pay[st + lane] : make_int2(0, 0);
        float bexp = 0.f;
        if (lane < cnt) {
            float s = usn + vs[pe.x] + wsr[pe.y] + ba;
            s = s > 0.f ? s : SLOPE * s;
            bexp = expf(s);
        }
        float bp = bexp;
        #pragma unroll
        for (int o = 32; o; o >>= 1) bp += __shfl_xor(bp, o, 64);
        float inv = 1.f / bp;
        int sub = lane >> 3;     // 0..7: edge slot
        int li = lane & 7;       // 0..7: dim octet
        float a[8] = {0.f,0.f,0.f,0.f,0.f,0.f,0.f,0.f};
        int groups = (cnt + 7) >> 3;
        for (int g = 0; g < groups; g++) {
            int esel = 8 * g + sub;
            float be = __shfl(bexp, esel, 64);      // 0 for invalid edges
            int de = __shfl(pe.x, esel, 64);
            int re = __shfl(pe.y, esel, 64);
            uint4 vv = *(const uint4*)(V16 + (size_t)de * 64 + li * 8);
            uint4 ww = *(const uint4*)(Wr16 + (size_t)re * 64 + li * 8);
            a[0] += be * (bfl(vv.x) + bfl(ww.x)); a[1] += be * (bfh(vv.x) + bfh(ww.x));
            a[2] += be * (bfl(vv.y) + bfl(ww.y)); a[3] += be * (bfh(vv.y) + bfh(ww.y));
            a[4] += be * (bfl(vv.z) + bfl(ww.z)); a[5] += be * (bfh(vv.z) + bfh(ww.z));
            a[6] += be * (bfl(vv.w) + bfl(ww.w)); a[7] += be * (bfh(vv.w) + bfh(ww.w));
        }
        #pragma unroll
        for (int m = 8; m <= 32; m <<= 1) {
            #pragma unroll
            for (int d = 0; d < 8; d++) a[d] += __shfl_xor(a[d], m, 64);
        }
        if (lane < 8) {
            float* hp = h + (size_t)n * 64 + lane * 8;
            float o[8];
            #pragma unroll
            for (int d = 0; d < 8; d++) o[d] = hp[d] + a[d] * inv;
            float4 o0 = make_float4(o[0], o[1], o[2], o[3]);
            float4 o1 = make_float4(o[4], o[5], o[6], o[7]);
            *(float4*)hp = o0;
            *(float4*)(hp + 4) = o1;
            uint4 pv;
            pv.x = (unsigned int)f2bf(o[0]) | ((unsigned int)f2bf(o[1]) << 16);
            pv.y = (unsigned int)f2bf(o[2]) | ((unsigned int)f2bf(o[3]) << 16);
            pv.z = (unsigned int)f2bf(o[4]) | ((unsigned int)f2bf(o[5]) << 16);
            pv.w = (unsigned int)f2bf(o[6]) | ((unsigned int)f2bf(o[7]) << 16);
            *(uint4*)(h16 + (size_t)n * 64 + lane * 8) = pv;
        }
        return;
    }

    // fallback: scalar two-pass (cnt > 64)
    float bp = 0.f;
    for (int k = lane; k < cnt; k += 64) {
        int2 p = pay[st + k];
        float s = usn + vs[p.x] + wsr[p.y] + ba;
        s = s > 0.f ? s : SLOPE * s;
        bp += expf(s);
    }
    #pragma unroll
    for (int o = 32; o; o >>= 1) bp += __shfl_xor(bp, o, 64);
    float inv = 1.f / bp;
    float acc = 0.f;
    for (int k = 0; k < cnt; k++) {
        int2 p = pay[st + k];
        float s = usn + vs[p.x] + wsr[p.y] + ba;
        s = s > 0.f ? s : SLOPE * s;
        float b = expf(s);
        float vv = bfl((unsigned int)V16[(size_t)p.x * 64 + lane] << 16 >> 16 << 16);
        // simpler: direct unpack
        vv = __uint_as_float((unsigned int)V16[(size_t)p.x * 64 + lane] << 16);
        float wv2 = __uint_as_float((unsigned int)Wr16[(size_t)p.y * 64 + lane] << 16);
        acc += b * (vv + wv2);
    }
    float u = h[(size_t)n * 64 + lane];
    float o = u + acc * inv;
    h[(size_t)n * 64 + lane] = o;
    h16[(size_t)n * 64 + lane] = f2bf(o);
}

// ---------------------------------------------------------------------------
// K7: relation pooling over bf16 h16 (128 B rows, 8 lanes/row, 32 edges/iter,
// 2-deep gather ILP + pay prefetch, LDS tree reduce).
// ---------------------------------------------------------------------------
__global__ __launch_bounds__(256) void k_relpool(const int2* __restrict__ pay,
        const int* __restrict__ start_rel, const int* __restrict__ cnt_rel,
        const unsigned short* __restrict__ h16, float* __restrict__ acc_rel) {
    int r = blockIdx.x / RSUB;
    int sub = blockIdx.x % RSUB;
    int st = start_rel[r];
    int cnt = cnt_rel[r];
    int t = threadIdx.x;
    int j = t >> 4;          // 0..15 edge slot
    int side = (t >> 3) & 1; // 0=src, 1=dst
    int li = t & 7;          // dim octet

    int chunk = (cnt + RSUB - 1) / RSUB;
    int k0 = sub * chunk;
    int k1 = min(k0 + chunk, cnt);
    int len = k1 - k0;

    float a[8] = {0.f,0.f,0.f,0.f,0.f,0.f,0.f,0.f};
    if (len > 0) {
        int steps = (len + 31) >> 5;
        int mA = j, mB = j + 16;
        bool vA = mA < len, vB = mB < len;
        int2 pA = vA ? pay[st + k0 + mA] : make_int2(0, 0);
        int2 pB = vB ? pay[st + k0 + mB] : make_int2(0, 0);
        for (int it = 0; it < steps; it++) {
            int nA = mA + 32, nB = mB + 32;
            bool wA = (it + 1 < steps) && (nA < len);
            bool wB = (it + 1 < steps) && (nB < len);
            int2 qA = wA ? pay[st + k0 + nA] : make_int2(0, 0);
            int2 qB = wB ? pay[st + k0 + nB] : make_int2(0, 0);
            int idxA = side ? pA.y : pA.x;
            int idxB = side ? pB.y : pB.x;
            uint4 hA = *(const uint4*)(h16 + (size_t)idxA * 64 + li * 8);
            uint4 hB = *(const uint4*)(h16 + (size_t)idxB * 64 + li * 8);
            if (vA) {
                a[0] += bfl(hA.x); a[1] += bfh(hA.x); a[2] += bfl(hA.y); a[3] += bfh(hA.y);
                a[4] += bfl(hA.z); a[5] += bfh(hA.z); a[6] += bfl(hA.w); a[7] += bfh(hA.w);
            }
            if (vB) {
                a[0] += bfl(hB.x); a[1] += bfh(hB.x); a[2] += bfl(hB.y); a[3] += bfh(hB.y);
                a[4] += bfl(hB.z); a[5] += bfh(hB.z); a[6] += bfl(hB.w); a[7] += bfh(hB.w);
            }
            pA = qA; pB = qB; mA = nA; mB = nB; vA = wA; vB = wB;
        }
    }
    __shared__ float red[256][8];
    #pragma unroll
    for (int d = 0; d < 8; d++) red[t][d] = a[d];
    __syncthreads();
    #pragma unroll
    for (int off = 128; off >= 16; off >>= 1) {
        if (t < off) {
            #pragma unroll
            for (int d = 0; d < 8; d++) red[t][d] += red[t + off][d];
        }
        __syncthreads();
    }
    if (t < 16) {
        int sd = (t >> 3) & 1;
        int ll = t & 7;
        float* dstp = &acc_rel[r * 128 + sd * 64 + ll * 8];
        #pragma unroll
        for (int d = 0; d < 8; d++) atomicAdd(dstp + d, red[t][d]);
    }
}

// K8: mean + h_rel = mean @ W_rel3.T + b_rel3
__global__ void k_relfin(const float* __restrict__ acc_rel, const int* __restrict__ cnt_rel,
                         const float* __restrict__ Qr, const float* __restrict__ W_rel3,
                         const float* __restrict__ b_rel3, float* __restrict__ out) {
    int g = blockIdx.x * 256 + threadIdx.x;
    if (g >= N_RELS * 64) return;
    int r = g >> 6;
    int j = g & 63;
    int cnt = cnt_rel[r];
    float invc = 1.f / (float)(cnt > 0 ? cnt : 1);
    float s = b_rel3[j];
    for (int k = 0; k < 128; k++) s += acc_rel[r * 128 + k] * invc * W_rel3[j * 192 + k];
    if (cnt > 0)
        for (int k = 0; k < 64; k++) s += Qr[r * 64 + k] * W_rel3[j * 192 + 128 + k];
    out[g] = s;
}

extern "C" void kernel_launch(void* const* d_in, const int* in_sizes, int n_in,
                              void* d_out, int out_size, void* d_ws, size_t ws_size,
                              hipStream_t stream) {
    const float* ent    = (const float*)d_in[0];
    const float* relE   = (const float*)d_in[1];
    const float* W_ent  = (const float*)d_in[2];
    const float* b_ent  = (const float*)d_in[3];
    const float* W_relL = (const float*)d_in[4];
    const float* b_relL = (const float*)d_in[5];
    const float* W_rel2 = (const float*)d_in[6];
    const float* b_rel2 = (const float*)d_in[7];
    const float* W_rel3 = (const float*)d_in[8];
    const float* b_rel3 = (const float*)d_in[9];
    const float* W_a    = (const float*)d_in[10];
    const float* b_a    = (const float*)d_in[11];
    const float* W_fc   = (const float*)d_in[12];
    const float* b_fc   = (const float*)d_in[13];
    const int* src = (const int*)d_in[14];
    const int* dst = (const int*)d_in[15];
    const int* rel = (const int*)d_in[16];
    float* out = (float*)d_out;

    char* ws = (char*)d_ws;
    size_t off = 0;
    auto alloc = [&](size_t bytes) -> void* {
        void* p = ws + off;
        off += (bytes + 255) & ~(size_t)255;
        return p;
    };
    float* Wcat = (float*)alloc(8192 * 4);
    float* dcat = (float*)alloc(128 * 4);
    float* MW  = (float*)alloc(4096 * 4);
    float* MQ  = (float*)alloc(4096 * 4);
    float* dW  = (float*)alloc(64 * 4);
    float* dQ  = (float*)alloc(64 * 4);
    unsigned short* V16 = (unsigned short*)alloc((size_t)N_NODES * 64 * 2);
    unsigned short* h16 = (unsigned short*)alloc((size_t)N_NODES * 64 * 2);
    float* us  = (float*)alloc((size_t)N_NODES * 4);
    float* vs  = (float*)alloc((size_t)N_NODES * 4);
    unsigned short* Wr16 = (unsigned short*)alloc((size_t)N_RELS * 64 * 2);
    float* Qr  = (float*)alloc((size_t)N_RELS * 64 * 4);
    float* wsr = (float*)alloc((size_t)N_RELS * 4);
    int* cnt_src   = (int*)alloc((size_t)N_NODES * 4);
    int* start_src = (int*)alloc((size_t)N_NODES * 4);
    int* cnts      = (int*)alloc((size_t)NROWS * 4);   // [0..499]=cnt_rel, [500..]=bucket_cnt
    int* starts    = (int*)alloc((size_t)NROWS * 4);
    int* blkhist   = (int*)alloc((size_t)NROWS * NB_E * 4);
    int* blkbase   = (int*)alloc((size_t)NROWS * NB_E * 4);
    int* stg_a     = (int*)alloc((size_t)N_EDGES * 4);
    int* stg_b     = (int*)alloc((size_t)N_EDGES * 4);
    int2* pay_src  = (int2*)alloc((size_t)N_EDGES * 8);
    int2* pay_rel  = (int2*)alloc((size_t)N_EDGES * 8);
    float* acc_rel = (float*)alloc((size_t)N_RELS * 128 * 4);

    int* cnt_rel    = cnts;
    int* bucket_cnt = cnts + N_RELS;

    k_zero<<<(NROWS + 255) / 256, 256, 0, stream>>>(cnts, NROWS);
    k_zero<<<(N_RELS * 128 + 255) / 256, 256, 0, stream>>>((int*)acc_rel, N_RELS * 128);

    k_fold<<<65, 256, 0, stream>>>(W_ent, b_ent, W_relL, b_relL, W_rel2, b_rel2,
                                   W_fc, b_fc, Wcat, dcat, MW, MQ, dW, dQ);
    k_node<<<(N_NODES + 63) / 64, 256, 0, stream>>>(ent, Wcat, dcat, W_a, out, V16, us, vs);
    k_relproj<<<125, 256, 0, stream>>>(relE, MW, MQ, dW, dQ, W_a, Wr16, Qr, wsr);
    k_hist<<<NB_E, 256, 0, stream>>>(src, rel, cnt_rel, bucket_cnt, blkhist);
    k_scan_two<<<2, 256, 0, stream>>>(cnt_rel, bucket_cnt, starts);
    k_scan_relblk<<<(NROWS * 64 + 255) / 256, 256, 0, stream>>>(starts, blkhist, blkbase);
    k_scatter<<<NB_E, 256, 0, stream>>>(src, dst, rel, blkbase, pay_rel, stg_a, stg_b);
    k_sortb<<<NBKT, 256, 0, stream>>>(stg_a, stg_b, starts, bucket_cnt,
                                      pay_src, start_src, cnt_src);
    k_attn<<<N_NODES / 4, 256, 0, stream>>>(pay_src, start_src, cnt_src,
                                            us, vs, wsr, V16, Wr16, b_a, out, h16);
    k_relpool<<<N_RELS * RSUB, 256, 0, stream>>>(pay_rel, starts, cnt_rel, h16, acc_rel);
    k_relfin<<<(N_RELS * 64 + 255) / 256, 256, 0, stream>>>(acc_rel, cnt_rel, Qr, W_rel3,
                                                            b_rel3, out + (size_t)N_NODES * 64);
}

// Round 9
// 310.331 us; speedup vs baseline: 1.4858x; 1.0293x over previous
//
#include <hip/hip_runtime.h>
#include <math.h>

#define N_NODES 100000
#define N_RELS  500
#define DIM     64
#define N_EDGES 1000000
#define SLOPE   0.01f
#define RSUB    16      // blocks per relation in pooling
#define SC_EDGES 2048   // edges per block in hist/scatter partition
#define NB_E    489     // ceil(N_EDGES / SC_EDGES)
#define NBKT    196     // src buckets (src >> 9, 512 nodes each)
#define BSH     9
#define NROWS   (N_RELS + NBKT)   // 696 rows in blkhist/blkbase
#define BMAX    5632    // LDS slots per bucket in k_sortb

// bf16 pack/unpack (round-to-nearest-even)
__device__ __forceinline__ unsigned short f2bf(float f) {
    unsigned int u = __float_as_uint(f);
    u += 0x7FFFu + ((u >> 16) & 1u);
    return (unsigned short)(u >> 16);
}
__device__ __forceinline__ float bfl(unsigned int u) { return __uint_as_float(u << 16); }
__device__ __forceinline__ float bfh(unsigned int u) { return __uint_as_float(u & 0xFFFF0000u); }

// ---------------------------------------------------------------------------
// K0: fold the small matrices.
// ---------------------------------------------------------------------------
__global__ void k_fold(const float* __restrict__ W_ent, const float* __restrict__ b_ent,
                       const float* __restrict__ W_relL, const float* __restrict__ b_relL,
                       const float* __restrict__ W_rel2, const float* __restrict__ b_rel2,
                       const float* __restrict__ W_fc, const float* __restrict__ b_fc,
                       float* __restrict__ Wcat, float* __restrict__ dcat,
                       float* __restrict__ MW, float* __restrict__ MQ,
                       float* __restrict__ dW, float* __restrict__ dQ) {
    int idx = blockIdx.x * 256 + threadIdx.x;
    if (idx < 8192) {
        int k = idx >> 7;
        int j2 = idx & 127;
        int jj = j2 & 63;
        int off = (j2 >> 6) * 64;
        float s = 0.f;
        for (int i = 0; i < 64; i++) s += W_fc[jj*192 + off + i] * W_ent[i*64 + k];
        Wcat[k*128 + j2] = s;
    } else if (idx < 12288) {
        int rem = idx - 8192;
        int j = rem >> 6, i = rem & 63;
        float s = 0.f;
        for (int k = 0; k < 64; k++) s += W_fc[j*192 + 128 + k] * W_relL[k*64 + i];
        MW[j*64 + i] = s;
    } else if (idx < 16384) {
        int rem = idx - 12288;
        int j = rem >> 6, i = rem & 63;
        float s = 0.f;
        for (int k = 0; k < 64; k++) s += W_rel2[j*64 + k] * W_relL[k*64 + i];
        MQ[j*64 + i] = s;
    } else if (idx < 16512) {
        int j2 = idx - 16384;
        int jj = j2 & 63;
        int off = (j2 >> 6) * 64;
        float s = 0.f;
        for (int i = 0; i < 64; i++) s += b_ent[i] * W_fc[jj*192 + off + i];
        dcat[j2] = s;
    } else if (idx < 16640) {
        int rem = idx - 16512;
        int vec = rem >> 6, j = rem & 63;
        if (vec == 0) {
            float s = b_fc[j];
            for (int k = 0; k < 64; k++) s += b_relL[k] * W_fc[j*192 + 128 + k];
            dW[j] = s;
        } else {
            float s = b_rel2[j];
            for (int k = 0; k < 64; k++) s += b_relL[k] * W_rel2[j*64 + k];
            dQ[j] = s;
        }
    }
}

// ---------------------------------------------------------------------------
// K1: per-node projections (LDS-tiled GEMM). U -> fp32 (output buffer);
// V -> bf16 shadow only.
// ---------------------------------------------------------------------------
__global__ __launch_bounds__(256) void k_node(const float* __restrict__ ent,
        const float* __restrict__ Wcat, const float* __restrict__ dcat,
        const float* __restrict__ W_a,
        float* __restrict__ Uout, unsigned short* __restrict__ V16,
        float* __restrict__ us, float* __restrict__ vs) {
    __shared__ float sA[64][68];
    __shared__ float sW[64][128];
    int t = threadIdx.x;
    int tile0 = blockIdx.x * 64;
    for (int i = t; i < 2048; i += 256)
        ((float4*)sW)[i] = ((const float4*)Wcat)[i];
    for (int f = t; f < 1024; f += 256) {
        int n = f >> 4, k4 = f & 15;
        float4 v4 = (tile0 + n < N_NODES)
            ? ((const float4*)(ent + (size_t)(tile0 + n) * 64))[k4]
            : make_float4(0.f, 0.f, 0.f, 0.f);
        *(float4*)&sA[n][k4 * 4] = v4;
    }
    __syncthreads();

    int ng = t >> 4;
    int jg = t & 15;
    int n0 = ng * 4;
    int j0 = jg * 8;

    float4 d0 = *(const float4*)(dcat + j0);
    float4 d1 = *(const float4*)(dcat + j0 + 4);
    float acc[4][8];
    #pragma unroll
    for (int a = 0; a < 4; a++) {
        acc[a][0] = d0.x; acc[a][1] = d0.y; acc[a][2] = d0.z; acc[a][3] = d0.w;
        acc[a][4] = d1.x; acc[a][5] = d1.y; acc[a][6] = d1.z; acc[a][7] = d1.w;
    }

    #pragma unroll 4
    for (int k = 0; k < 64; k++) {
        float4 w0 = *(const float4*)&sW[k][j0];
        float4 w1 = *(const float4*)&sW[k][j0 + 4];
        float e0 = sA[n0][k], e1 = sA[n0+1][k], e2 = sA[n0+2][k], e3 = sA[n0+3][k];
        float e[4] = {e0, e1, e2, e3};
        #pragma unroll
        for (int a = 0; a < 4; a++) {
            acc[a][0] += e[a] * w0.x; acc[a][1] += e[a] * w0.y;
            acc[a][2] += e[a] * w0.z; acc[a][3] += e[a] * w0.w;
            acc[a][4] += e[a] * w1.x; acc[a][5] += e[a] * w1.y;
            acc[a][6] += e[a] * w1.z; acc[a][7] += e[a] * w1.w;
        }
    }

    int jw = j0 & 63;
    float4 wa0 = *(const float4*)(W_a + jw);
    float4 wa1 = *(const float4*)(W_a + jw + 4);
    float part[4];
    #pragma unroll
    for (int a = 0; a < 4; a++) {
        part[a] = acc[a][0]*wa0.x + acc[a][1]*wa0.y + acc[a][2]*wa0.z + acc[a][3]*wa0.w
                + acc[a][4]*wa1.x + acc[a][5]*wa1.y + acc[a][6]*wa1.z + acc[a][7]*wa1.w;
    }
    #pragma unroll
    for (int m = 1; m <= 4; m <<= 1) {
        #pragma unroll
        for (int a = 0; a < 4; a++) part[a] += __shfl_xor(part[a], m, 64);
    }
    if ((jg & 7) == 0) {
        float* sv = (jg < 8) ? us : vs;
        #pragma unroll
        for (int a = 0; a < 4; a++)
            if (tile0 + n0 + a < N_NODES) sv[tile0 + n0 + a] = part[a];
    }

    #pragma unroll
    for (int a = 0; a < 4; a++) {
        int n = tile0 + n0 + a;
        if (n >= N_NODES) break;
        if (jg < 8) {
            float4 o0 = make_float4(acc[a][0], acc[a][1], acc[a][2], acc[a][3]);
            float4 o1 = make_float4(acc[a][4], acc[a][5], acc[a][6], acc[a][7]);
            float* base = Uout + (size_t)n * 64 + j0;
            *(float4*)(base) = o0;
            *(float4*)(base + 4) = o1;
        } else {
            uint4 pv;
            pv.x = (unsigned int)f2bf(acc[a][0]) | ((unsigned int)f2bf(acc[a][1]) << 16);
            pv.y = (unsigned int)f2bf(acc[a][2]) | ((unsigned int)f2bf(acc[a][3]) << 16);
            pv.z = (unsigned int)f2bf(acc[a][4]) | ((unsigned int)f2bf(acc[a][5]) << 16);
            pv.w = (unsigned int)f2bf(acc[a][6]) | ((unsigned int)f2bf(acc[a][7]) << 16);
            *(uint4*)(V16 + (size_t)n * 64 + (j0 - 64)) = pv;
        }
    }
}

// K2: per-relation projections. Wr -> bf16 shadow; Qr fp32; wsr fp32.
__global__ __launch_bounds__(256, 2) void k_relproj(const float* __restrict__ relE,
        const float* __restrict__ MW, const float* __restrict__ MQ,
        const float* __restrict__ dW, const float* __restrict__ dQ,
        const float* __restrict__ W_a,
        unsigned short* __restrict__ Wr16, float* __restrict__ Qr, float* __restrict__ wsr) {
    int lane = threadIdx.x & 63;
    int wv = threadIdx.x >> 6;
    float mw[64], mq[64];
    #pragma unroll
    for (int i = 0; i < 64; i++) { mw[i] = MW[lane*64 + i]; mq[i] = MQ[lane*64 + i]; }
    float dw = dW[lane], dq = dQ[lane], wa = W_a[lane];
    int r = blockIdx.x * 4 + wv;
    if (r >= N_RELS) return;
    float e = relE[(size_t)r * 64 + lane];
    float w = dw, q = dq;
    #pragma unroll
    for (int i = 0; i < 64; i++) {
        float ei = __shfl(e, i, 64);
        w += ei * mw[i];
        q += ei * mq[i];
    }
    Wr16[(size_t)r * 64 + lane] = f2bf(w);
    Qr[(size_t)r * 64 + lane] = q;
    float tw = w * wa;
    #pragma unroll
    for (int o = 32; o; o >>= 1) tw += __shfl_xor(tw, o, 64);
    if (lane == 0) wsr[r] = tw;
}

__global__ void k_zero(int* __restrict__ a, int n) {
    int g = blockIdx.x * 256 + threadIdx.x;
    if (g < n) a[g] = 0;
}

// ---------------------------------------------------------------------------
// K3: histogram (LDS hists: 500 rels + 196 src-buckets; transposed blkhist).
// ---------------------------------------------------------------------------
__global__ __launch_bounds__(256) void k_hist(const int* __restrict__ src, const int* __restrict__ rel,
        int* __restrict__ cnt_rel, int* __restrict__ bucket_cnt, int* __restrict__ blkhist) {
    __shared__ int lcntR[N_RELS];
    __shared__ int lcntS[NBKT];
    int t = threadIdx.x;
    for (int r = t; r < N_RELS; r += 256) lcntR[r] = 0;
    for (int b = t; b < NBKT; b += 256) lcntS[b] = 0;
    __syncthreads();
    int base = blockIdx.x * SC_EDGES;
    if (base + SC_EDGES <= N_EDGES) {
        int e0 = base + t * 8;
        int4 sa = *(const int4*)(src + e0);
        int4 sb = *(const int4*)(src + e0 + 4);
        int4 ra = *(const int4*)(rel + e0);
        int4 rb = *(const int4*)(rel + e0 + 4);
        atomicAdd(&lcntS[sa.x >> BSH], 1); atomicAdd(&lcntS[sa.y >> BSH], 1);
        atomicAdd(&lcntS[sa.z >> BSH], 1); atomicAdd(&lcntS[sa.w >> BSH], 1);
        atomicAdd(&lcntS[sb.x >> BSH], 1); atomicAdd(&lcntS[sb.y >> BSH], 1);
        atomicAdd(&lcntS[sb.z >> BSH], 1); atomicAdd(&lcntS[sb.w >> BSH], 1);
        atomicAdd(&lcntR[ra.x], 1); atomicAdd(&lcntR[ra.y], 1);
        atomicAdd(&lcntR[ra.z], 1); atomicAdd(&lcntR[ra.w], 1);
        atomicAdd(&lcntR[rb.x], 1); atomicAdd(&lcntR[rb.y], 1);
        atomicAdd(&lcntR[rb.z], 1); atomicAdd(&lcntR[rb.w], 1);
    } else {
        for (int g = base + t; g < N_EDGES; g += 256) {
            atomicAdd(&lcntS[src[g] >> BSH], 1);
            atomicAdd(&lcntR[rel[g]], 1);
        }
    }
    __syncthreads();
    for (int r = t; r < N_RELS; r += 256) {
        int c = lcntR[r];
        blkhist[(size_t)r * NB_E + blockIdx.x] = c;
        if (c) atomicAdd(&cnt_rel[r], c);
    }
    for (int b = t; b < NBKT; b += 256) {
        int c = lcntS[b];
        blkhist[(size_t)(N_RELS + b) * NB_E + blockIdx.x] = c;
        if (c) atomicAdd(&bucket_cnt[b], c);
    }
}

// K4a: two small exclusive scans (rels, buckets).
__global__ void k_scan_two(const int* __restrict__ cnt_rel, const int* __restrict__ bucket_cnt,
                           int* __restrict__ starts) {
    __shared__ int tot[256];
    int t = threadIdx.x;
    const int* cnt = blockIdx.x ? bucket_cnt : cnt_rel;
    int n = blockIdx.x ? NBKT : N_RELS;
    int* out = starts + (blockIdx.x ? N_RELS : 0);
    int myv[4];
    int mySum = 0;
    for (int q = 0; q < 4; q++) {
        int g = t * 4 + q;
        int v = (g < n) ? cnt[g] : 0;
        myv[q] = v; mySum += v;
    }
    tot[t] = mySum;
    __syncthreads();
    for (int o = 1; o < 256; o <<= 1) {
        int u = (t >= o) ? tot[t - o] : 0;
        __syncthreads();
        tot[t] += u;
        __syncthreads();
    }
    int run = tot[t] - mySum;
    for (int q = 0; q < 4; q++) {
        int g = t * 4 + q;
        if (g < n) out[g] = run;
        run += myv[q];
    }
}

// K4b: per-(row, block) bases; one wave per row.
__global__ __launch_bounds__(256) void k_scan_relblk(const int* __restrict__ starts,
        const int* __restrict__ blkhist, int* __restrict__ blkbase) {
    int lane = threadIdx.x & 63;
    int row = (blockIdx.x * 256 + threadIdx.x) >> 6;
    if (row >= NROWS) return;
    int run = starts[row];
    for (int base = 0; base < NB_E; base += 64) {
        int b = base + lane;
        int v = (b < NB_E) ? blkhist[(size_t)row * NB_E + b] : 0;
        int x = v;
        #pragma unroll
        for (int o = 1; o < 64; o <<= 1) {
            int y = __shfl_up(x, o, 64);
            if (lane >= o) x += y;
        }
        if (b < NB_E) blkbase[(size_t)row * NB_E + b] = run + (x - v);
        run += __shfl(x, 63, 64);
    }
}

// ---------------------------------------------------------------------------
// K5: pass-A scatter (no global atomics).
// ---------------------------------------------------------------------------
__global__ __launch_bounds__(256) void k_scatter(const int* __restrict__ src, const int* __restrict__ dst,
        const int* __restrict__ rel, const int* __restrict__ blkbase,
        int2* __restrict__ pay_rel, int* __restrict__ stg_a, int* __restrict__ stg_b) {
    __shared__ int lbaseR[N_RELS];
    __shared__ int loffR[N_RELS];
    __shared__ int lbaseS[NBKT];
    __shared__ int loffS[NBKT];
    int t = threadIdx.x;
    for (int r = t; r < N_RELS; r += 256) {
        lbaseR[r] = blkbase[(size_t)r * NB_E + blockIdx.x];
        loffR[r] = 0;
    }
    for (int b = t; b < NBKT; b += 256) {
        lbaseS[b] = blkbase[(size_t)(N_RELS + b) * NB_E + blockIdx.x];
        loffS[b] = 0;
    }
    __syncthreads();
    int base = blockIdx.x * SC_EDGES;
    if (base + SC_EDGES <= N_EDGES) {
        int e0 = base + t * 8;
        int4 sa = *(const int4*)(src + e0);
        int4 sb = *(const int4*)(src + e0 + 4);
        int4 da = *(const int4*)(dst + e0);
        int4 db = *(const int4*)(dst + e0 + 4);
        int4 ra = *(const int4*)(rel + e0);
        int4 rb = *(const int4*)(rel + e0 + 4);
        int s[8] = {sa.x, sa.y, sa.z, sa.w, sb.x, sb.y, sb.z, sb.w};
        int d[8] = {da.x, da.y, da.z, da.w, db.x, db.y, db.z, db.w};
        int r8[8] = {ra.x, ra.y, ra.z, ra.w, rb.x, rb.y, rb.z, rb.w};
        int p[8], q[8];
        #pragma unroll
        for (int j = 0; j < 8; j++) q[j] = lbaseR[r8[j]] + atomicAdd(&loffR[r8[j]], 1);
        #pragma unroll
        for (int j = 0; j < 8; j++) p[j] = lbaseS[s[j] >> BSH] + atomicAdd(&loffS[s[j] >> BSH], 1);
        #pragma unroll
        for (int j = 0; j < 8; j++) pay_rel[q[j]] = make_int2(s[j], d[j]);
        #pragma unroll
        for (int j = 0; j < 8; j++) stg_a[p[j]] = d[j];
        #pragma unroll
        for (int j = 0; j < 8; j++) stg_b[p[j]] = ((s[j] & 511) << 9) | r8[j];
    } else {
        for (int g = base + t; g < N_EDGES; g += 256) {
            int s = src[g], d = dst[g], r = rel[g];
            int q = lbaseR[r] + atomicAdd(&loffR[r], 1);
            pay_rel[q] = make_int2(s, d);
            int sb2 = s >> BSH;
            int p = lbaseS[sb2] + atomicAdd(&loffS[sb2], 1);
            stg_a[p] = d;
            stg_b[p] = ((s & 511) << 9) | r;
        }
    }
}

// ---------------------------------------------------------------------------
// K5b: pass-B bucket counting sort -> pay_src + start/cnt_src. Also computes
// per-edge attention weight b = exp(leaky(us+vs+wsr+ba)) -> pay_b (coalesced)
// and per-node bsum (LDS float atomics) -> bsum_arr.
// ---------------------------------------------------------------------------
__global__ __launch_bounds__(256) void k_sortb(const int* __restrict__ stg_a,
        const int* __restrict__ stg_b, const int* __restrict__ starts,
        const int* __restrict__ bucket_cnt,
        const float* __restrict__ us, const float* __restrict__ vs,
        const float* __restrict__ wsr, const float* __restrict__ b_a_p,
        int2* __restrict__ pay_src, float* __restrict__ pay_b,
        int* __restrict__ start_src, int* __restrict__ cnt_src,
        float* __restrict__ bsum_arr) {
    __shared__ int hist[512];
    __shared__ int lstart[512];
    __shared__ int loff[512];
    __shared__ int tot[256];
    __shared__ float lbsum[512];
    __shared__ int2 lpay[BMAX];
    int bkt = blockIdx.x;
    int base = starts[N_RELS + bkt];
    int n = bucket_cnt[bkt];
    int t = threadIdx.x;
    float ba = b_a_p[0];
    hist[t] = 0; hist[t + 256] = 0;
    lbsum[t] = 0.f; lbsum[t + 256] = 0.f;
    __syncthreads();
    for (int i = t; i < n; i += 256)
        atomicAdd(&hist[stg_b[base + i] >> 9], 1);
    __syncthreads();
    int v0 = hist[t * 2], v1 = hist[t * 2 + 1];
    int mySum = v0 + v1;
    tot[t] = mySum;
    __syncthreads();
    for (int o = 1; o < 256; o <<= 1) {
        int u = (t >= o) ? tot[t - o] : 0;
        __syncthreads();
        tot[t] += u;
        __syncthreads();
    }
    int run = tot[t] - mySum;
    lstart[t * 2] = run;
    lstart[t * 2 + 1] = run + v0;
    loff[t * 2] = 0;
    loff[t * 2 + 1] = 0;
    int node0 = bkt * 512 + t * 2;
    if (node0 < N_NODES) { start_src[node0] = base + run; cnt_src[node0] = v0; }
    if (node0 + 1 < N_NODES) { start_src[node0 + 1] = base + run + v0; cnt_src[node0 + 1] = v1; }
    __syncthreads();
    bool fits = (n <= BMAX);
    for (int i = t; i < n; i += 256) {
        int bb = stg_b[base + i];
        int d = stg_a[base + i];
        int lo = bb >> 9;
        int pos = lstart[lo] + atomicAdd(&loff[lo], 1);
        if (fits) {
            lpay[pos] = make_int2(d, bb);
        } else {
            int r = bb & 511;
            int s = bkt * 512 + lo;
            float t0 = us[s] + vs[d] + wsr[r] + ba;
            t0 = t0 > 0.f ? t0 : SLOPE * t0;
            float b = expf(t0);
            pay_src[base + pos] = make_int2(d, r);
            pay_b[base + pos] = b;
            atomicAdd(&lbsum[lo], b);
        }
    }
    __syncthreads();
    if (fits) {
        for (int i = t; i < n; i += 256) {
            int2 pr = lpay[i];
            int bb = pr.y;
            int lo = bb >> 9;
            int r = bb & 511;
            int s = bkt * 512 + lo;
            float t0 = us[s] + vs[pr.x] + wsr[r] + ba;
            t0 = t0 > 0.f ? t0 : SLOPE * t0;
            float b = expf(t0);
            pay_src[base + i] = make_int2(pr.x, r);
            pay_b[base + i] = b;
            atomicAdd(&lbsum[lo], b);
        }
        __syncthreads();
    }
    if (node0 < N_NODES) bsum_arr[node0] = lbsum[t * 2];
    if (node0 + 1 < N_NODES) bsum_arr[node0 + 1] = lbsum[t * 2 + 1];
}

// ---------------------------------------------------------------------------
// K6: aggregation. 4 nodes per wave (16 lanes each, 8 lanes per edge row);
// b/bsum precomputed; payload broadcast via same-address loads (no shfl in
// loop); dual-edge unroll = 4 gather rows in flight per lane.
// ---------------------------------------------------------------------------
__global__ __launch_bounds__(256) void k_attn(const int2* __restrict__ pay,
        const float* __restrict__ pay_b,
        const int* __restrict__ start_src, const int* __restrict__ cnt_src,
        const float* __restrict__ bsum_arr,
        const unsigned short* __restrict__ V16, const unsigned short* __restrict__ Wr16,
        float* __restrict__ h, unsigned short* __restrict__ h16) {
    int lane = threadIdx.x & 63;
    int wv = threadIdx.x >> 6;
    int quarter = lane >> 4;
    int lq = lane & 15;
    int slot = lq >> 3;      // 0/1: even/odd edge stream
    int li = lq & 7;         // dim octet
    int n = blockIdx.x * 16 + wv * 4 + quarter;
    if (n >= N_NODES) return;
    int st = start_src[n];
    int cnt = cnt_src[n];
    if (cnt == 0) {
        if (lq < 8) {
            float* hp = h + (size_t)n * 64 + lq * 8;
            *(float4*)hp = make_float4(0.f, 0.f, 0.f, 0.f);
            *(float4*)(hp + 4) = make_float4(0.f, 0.f, 0.f, 0.f);
            *(uint4*)(h16 + (size_t)n * 64 + lq * 8) = make_uint4(0, 0, 0, 0);
        }
        return;
    }
    float inv = 1.f / bsum_arr[n];
    float a[8] = {0.f, 0.f, 0.f, 0.f, 0.f, 0.f, 0.f, 0.f};
    for (int e = slot; e < cnt; e += 4) {
        int eB = e + 2;
        bool vB = eB < cnt;
        int eBc = vB ? eB : e;
        float bA = pay_b[st + e];
        float bB = vB ? pay_b[st + eB] : 0.f;
        int2 pA = pay[st + e];
        int2 pB = pay[st + eBc];
        uint4 vvA = *(const uint4*)(V16 + (size_t)pA.x * 64 + li * 8);
        uint4 wwA = *(const uint4*)(Wr16 + (size_t)pA.y * 64 + li * 8);
        uint4 vvB = *(const uint4*)(V16 + (size_t)pB.x * 64 + li * 8);
        uint4 wwB = *(const uint4*)(Wr16 + (size_t)pB.y * 64 + li * 8);
        a[0] += bA * (bfl(vvA.x) + bfl(wwA.x)) + bB * (bfl(vvB.x) + bfl(wwB.x));
        a[1] += bA * (bfh(vvA.x) + bfh(wwA.x)) + bB * (bfh(vvB.x) + bfh(wwB.x));
        a[2] += bA * (bfl(vvA.y) + bfl(wwA.y)) + bB * (bfl(vvB.y) + bfl(wwB.y));
        a[3] += bA * (bfh(vvA.y) + bfh(wwA.y)) + bB * (bfh(vvB.y) + bfh(wwB.y));
        a[4] += bA * (bfl(vvA.z) + bfl(wwA.z)) + bB * (bfl(vvB.z) + bfl(wwB.z));
        a[5] += bA * (bfh(vvA.z) + bfh(wwA.z)) + bB * (bfh(vvB.z) + bfh(wwB.z));
        a[6] += bA * (bfl(vvA.w) + bfl(wwA.w)) + bB * (bfl(vvB.w) + bfl(wwB.w));
        a[7] += bA * (bfh(vvA.w) + bfh(wwA.w)) + bB * (bfh(vvB.w) + bfh(wwB.w));
    }
    #pragma unroll
    for (int d = 0; d < 8; d++) a[d] += __shfl_xor(a[d], 8, 64);
    if (slot == 0) {
        float* hp = h + (size_t)n * 64 + li * 8;
        float o[8];
        #pragma unroll
        for (int d = 0; d < 8; d++) o[d] = hp[d] + a[d] * inv;
        *(float4*)hp = make_float4(o[0], o[1], o[2], o[3]);
        *(float4*)(hp + 4) = make_float4(o[4], o[5], o[6], o[7]);
        uint4 pv;
        pv.x = (unsigned int)f2bf(o[0]) | ((unsigned int)f2bf(o[1]) << 16);
        pv.y = (unsigned int)f2bf(o[2]) | ((unsigned int)f2bf(o[3]) << 16);
        pv.z = (unsigned int)f2bf(o[4]) | ((unsigned int)f2bf(o[5]) << 16);
        pv.w = (unsigned int)f2bf(o[6]) | ((unsigned int)f2bf(o[7]) << 16);
        *(uint4*)(h16 + (size_t)n * 64 + li * 8) = pv;
    }
}

// ---------------------------------------------------------------------------
// K7: relation pooling over bf16 h16 (128 B rows, 8 lanes/row, 32 edges/iter,
// 2-deep gather ILP + pay prefetch, LDS tree reduce).
// ---------------------------------------------------------------------------
__global__ __launch_bounds__(256) void k_relpool(const int2* __restrict__ pay,
        const int* __restrict__ start_rel, const int* __restrict__ cnt_rel,
        const unsigned short* __restrict__ h16, float* __restrict__ acc_rel) {
    int r = blockIdx.x / RSUB;
    int sub = blockIdx.x % RSUB;
    int st = start_rel[r];
    int cnt = cnt_rel[r];
    int t = threadIdx.x;
    int j = t >> 4;          // 0..15 edge slot
    int side = (t >> 3) & 1; // 0=src, 1=dst
    int li = t & 7;          // dim octet

    int chunk = (cnt + RSUB - 1) / RSUB;
    int k0 = sub * chunk;
    int k1 = min(k0 + chunk, cnt);
    int len = k1 - k0;

    float a[8] = {0.f,0.f,0.f,0.f,0.f,0.f,0.f,0.f};
    if (len > 0) {
        int steps = (len + 31) >> 5;
        int mA = j, mB = j + 16;
        bool vA = mA < len, vB = mB < len;
        int2 pA = vA ? pay[st + k0 + mA] : make_int2(0, 0);
        int2 pB = vB ? pay[st + k0 + mB] : make_int2(0, 0);
        for (int it = 0; it < steps; it++) {
            int nA = mA + 32, nB = mB + 32;
            bool wA = (it + 1 < steps) && (nA < len);
            bool wB = (it + 1 < steps) && (nB < len);
            int2 qA = wA ? pay[st + k0 + nA] : make_int2(0, 0);
            int2 qB = wB ? pay[st + k0 + nB] : make_int2(0, 0);
            int idxA = side ? pA.y : pA.x;
            int idxB = side ? pB.y : pB.x;
            uint4 hA = *(const uint4*)(h16 + (size_t)idxA * 64 + li * 8);
            uint4 hB = *(const uint4*)(h16 + (size_t)idxB * 64 + li * 8);
            if (vA) {
                a[0] += bfl(hA.x); a[1] += bfh(hA.x); a[2] += bfl(hA.y); a[3] += bfh(hA.y);
                a[4] += bfl(hA.z); a[5] += bfh(hA.z); a[6] += bfl(hA.w); a[7] += bfh(hA.w);
            }
            if (vB) {
                a[0] += bfl(hB.x); a[1] += bfh(hB.x); a[2] += bfl(hB.y); a[3] += bfh(hB.y);
                a[4] += bfl(hB.z); a[5] += bfh(hB.z); a[6] += bfl(hB.w); a[7] += bfh(hB.w);
            }
            pA = qA; pB = qB; mA = nA; mB = nB; vA = wA; vB = wB;
        }
    }
    __shared__ float red[256][8];
    #pragma unroll
    for (int d = 0; d < 8; d++) red[t][d] = a[d];
    __syncthreads();
    #pragma unroll
    for (int off = 128; off >= 16; off >>= 1) {
        if (t < off) {
            #pragma unroll
            for (int d = 0; d < 8; d++) red[t][d] += red[t + off][d];
        }
        __syncthreads();
    }
    if (t < 16) {
        int sd = (t >> 3) & 1;
        int ll = t & 7;
        float* dstp = &acc_rel[r * 128 + sd * 64 + ll * 8];
        #pragma unroll
        for (int d = 0; d < 8; d++) atomicAdd(dstp + d, red[t][d]);
    }
}

// K8: mean + h_rel = mean @ W_rel3.T + b_rel3
__global__ void k_relfin(const float* __restrict__ acc_rel, const int* __restrict__ cnt_rel,
                         const float* __restrict__ Qr, const float* __restrict__ W_rel3,
                         const float* __restrict__ b_rel3, float* __restrict__ out) {
    int g = blockIdx.x * 256 + threadIdx.x;
    if (g >= N_RELS * 64) return;
    int r = g >> 6;
    int j = g & 63;
    int cnt = cnt_rel[r];
    float invc = 1.f / (float)(cnt > 0 ? cnt : 1);
    float s = b_rel3[j];
    for (int k = 0; k < 128; k++) s += acc_rel[r * 128 + k] * invc * W_rel3[j * 192 + k];
    if (cnt > 0)
        for (int k = 0; k < 64; k++) s += Qr[r * 64 + k] * W_rel3[j * 192 + 128 + k];
    out[g] = s;
}

extern "C" void kernel_launch(void* const* d_in, const int* in_sizes, int n_in,
                              void* d_out, int out_size, void* d_ws, size_t ws_size,
                              hipStream_t stream) {
    const float* ent    = (const float*)d_in[0];
    const float* relE   = (const float*)d_in[1];
    const float* W_ent  = (const float*)d_in[2];
    const float* b_ent  = (const float*)d_in[3];
    const float* W_relL = (const float*)d_in[4];
    const float* b_relL = (const float*)d_in[5];
    const float* W_rel2 = (const float*)d_in[6];
    const float* b_rel2 = (const float*)d_in[7];
    const float* W_rel3 = (const float*)d_in[8];
    const float* b_rel3 = (const float*)d_in[9];
    const float* W_a    = (const float*)d_in[10];
    const float* b_a    = (const float*)d_in[11];
    const float* W_fc   = (const float*)d_in[12];
    const float* b_fc   = (const float*)d_in[13];
    const int* src = (const int*)d_in[14];
    const int* dst = (const int*)d_in[15];
    const int* rel = (const int*)d_in[16];
    float* out = (float*)d_out;

    char* ws = (char*)d_ws;
    size_t off = 0;
    auto alloc = [&](size_t bytes) -> void* {
        void* p = ws + off;
        off += (bytes + 255) & ~(size_t)255;
        return p;
    };
    float* Wcat = (float*)alloc(8192 * 4);
    float* dcat = (float*)alloc(128 * 4);
    float* MW  = (float*)alloc(4096 * 4);
    float* MQ  = (float*)alloc(4096 * 4);
    float* dW  = (float*)alloc(64 * 4);
    float* dQ  = (float*)alloc(64 * 4);
    unsigned short* V16 = (unsigned short*)alloc((size_t)N_NODES * 64 * 2);
    unsigned short* h16 = (unsigned short*)alloc((size_t)N_NODES * 64 * 2);
    float* us  = (float*)alloc((size_t)N_NODES * 4);
    float* vs  = (float*)alloc((size_t)N_NODES * 4);
    unsigned short* Wr16 = (unsigned short*)alloc((size_t)N_RELS * 64 * 2);
    float* Qr  = (float*)alloc((size_t)N_RELS * 64 * 4);
    float* wsr = (float*)alloc((size_t)N_RELS * 4);
    int* cnt_src   = (int*)alloc((size_t)N_NODES * 4);
    int* start_src = (int*)alloc((size_t)N_NODES * 4);
    float* bsum    = (float*)alloc((size_t)N_NODES * 4);
    int* cnts      = (int*)alloc((size_t)NROWS * 4);   // [0..499]=cnt_rel, [500..]=bucket_cnt
    int* starts    = (int*)alloc((size_t)NROWS * 4);
    int* blkhist   = (int*)alloc((size_t)NROWS * NB_E * 4);
    int* blkbase   = (int*)alloc((size_t)NROWS * NB_E * 4);
    int* stg_a     = (int*)alloc((size_t)N_EDGES * 4);
    int* stg_b     = (int*)alloc((size_t)N_EDGES * 4);
    int2* pay_src  = (int2*)alloc((size_t)N_EDGES * 8);
    float* pay_b   = (float*)alloc((size_t)N_EDGES * 4);
    int2* pay_rel  = (int2*)alloc((size_t)N_EDGES * 8);
    float* acc_rel = (float*)alloc((size_t)N_RELS * 128 * 4);

    int* cnt_rel    = cnts;
    int* bucket_cnt = cnts + N_RELS;

    k_zero<<<(NROWS + 255) / 256, 256, 0, stream>>>(cnts, NROWS);
    k_zero<<<(N_RELS * 128 + 255) / 256, 256, 0, stream>>>((int*)acc_rel, N_RELS * 128);

    k_fold<<<65, 256, 0, stream>>>(W_ent, b_ent, W_relL, b_relL, W_rel2, b_rel2,
                                   W_fc, b_fc, Wcat, dcat, MW, MQ, dW, dQ);
    k_node<<<(N_NODES + 63) / 64, 256, 0, stream>>>(ent, Wcat, dcat, W_a, out, V16, us, vs);
    k_relproj<<<125, 256, 0, stream>>>(relE, MW, MQ, dW, dQ, W_a, Wr16, Qr, wsr);
    k_hist<<<NB_E, 256, 0, stream>>>(src, rel, cnt_rel, bucket_cnt, blkhist);
    k_scan_two<<<2, 256, 0, stream>>>(cnt_rel, bucket_cnt, starts);
    k_scan_relblk<<<(NROWS * 64 + 255) / 256, 256, 0, stream>>>(starts, blkhist, blkbase);
    k_scatter<<<NB_E, 256, 0, stream>>>(src, dst, rel, blkbase, pay_rel, stg_a, stg_b);
    k_sortb<<<NBKT, 256, 0, stream>>>(stg_a, stg_b, starts, bucket_cnt,
                                      us, vs, wsr, b_a,
                                      pay_src, pay_b, start_src, cnt_src, bsum);
    k_attn<<<(N_NODES + 15) / 16, 256, 0, stream>>>(pay_src, pay_b, start_src, cnt_src,
                                                    bsum, V16, Wr16, out, h16);
    k_relpool<<<N_RELS * RSUB, 256, 0, stream>>>(pay_rel, starts, cnt_rel, h16, acc_rel);
    k_relfin<<<(N_RELS * 64 + 255) / 256, 256, 0, stream>>>(acc_rel, cnt_rel, Qr, W_rel3,
                                                            b_rel3, out + (size_t)N_NODES * 64);
}